// Round 3
// baseline (636.205 us; speedup 1.0000x reference)
//
#include <hip/hip_runtime.h>
#include <hip/hip_bf16.h>

// Dtype contract (established rounds 0-2): ALL inputs fp32, OUTPUT fp32
// (harness compares in bf16 domain with 2% threshold).
// Dims: B=1, T=2048, C=1024, H=16, HKV=4, DH=64, WIN=128.

typedef __hip_bfloat16 bf16;

#define T_DIM 2048
#define C_DIM 1024
#define H_NUM 16
#define HKV_NUM 4
#define DH 64

// ---------------------------------------------------------------------------
// Generic tiled GEMM: C[M,N] = A[M,K] @ B[K,N], fp32 in, fp32 accumulate.
// 64x64 block tile, 16x16 threads with 4x4 micro-tile, K-tile 16.
// ---------------------------------------------------------------------------
__global__ __launch_bounds__(256) void gemm_kernel(
    const float* __restrict__ A, const float* __restrict__ B,
    float* __restrict__ C, int M, int N, int K) {
  __shared__ float As[16][68];  // [k][m], pad 68 keeps float4 16B-aligned
  __shared__ float Bs[16][68];  // [k][n]
  const int tid = threadIdx.x;
  const int tx = tid & 15, ty = tid >> 4;
  const int m0 = blockIdx.y * 64, n0 = blockIdx.x * 64;
  const int i4 = tid * 4;
  const int am = i4 >> 4, ak = i4 & 15;   // A: 64 rows x 16 k
  const int bk = i4 >> 6, bn = i4 & 63;   // B: 16 k x 64 n
  float acc[4][4] = {};
  for (int k0 = 0; k0 < K; k0 += 16) {
    float4 ra = *(const float4*)(A + (size_t)(m0 + am) * K + k0 + ak);
    float4 rb = *(const float4*)(B + (size_t)(k0 + bk) * N + n0 + bn);
    As[ak + 0][am] = ra.x;
    As[ak + 1][am] = ra.y;
    As[ak + 2][am] = ra.z;
    As[ak + 3][am] = ra.w;
    Bs[bk][bn + 0] = rb.x;
    Bs[bk][bn + 1] = rb.y;
    Bs[bk][bn + 2] = rb.z;
    Bs[bk][bn + 3] = rb.w;
    __syncthreads();
#pragma unroll
    for (int kk = 0; kk < 16; ++kk) {
      float a[4], b[4];
      *(float4*)a = *(const float4*)&As[kk][ty * 4];
      *(float4*)b = *(const float4*)&Bs[kk][tx * 4];
#pragma unroll
      for (int i = 0; i < 4; ++i)
#pragma unroll
        for (int j = 0; j < 4; ++j) acc[i][j] = fmaf(a[i], b[j], acc[i][j]);
    }
    __syncthreads();
  }
#pragma unroll
  for (int i = 0; i < 4; ++i)
#pragma unroll
    for (int j = 0; j < 4; ++j)
      C[(size_t)(m0 + ty * 4 + i) * N + n0 + tx * 4 + j] = acc[i][j];
}

// ---------------------------------------------------------------------------
// Gate logits: g[t,h] = x[t,:] @ Wg[:,h] + bg[h]   (T x 16, K=1024)
// ---------------------------------------------------------------------------
__global__ __launch_bounds__(256) void gate_kernel(
    const float* __restrict__ x, const float* __restrict__ Wg,
    const float* __restrict__ bg, float* __restrict__ g) {
  int idx = blockIdx.x * 256 + threadIdx.x;  // t*16 + h
  int t = idx >> 4, h = idx & 15;
  const float* xr = x + (size_t)t * C_DIM;
  float acc = 0.f;
  for (int c = 0; c < C_DIM; ++c) acc = fmaf(xr[c], Wg[c * 16 + h], acc);
  g[idx] = acc + bg[h];
}

// ---------------------------------------------------------------------------
// RoPE in-place on q [T, H*64] and k [T, HKV*64]. Pair (j, j+32), j<32.
// ---------------------------------------------------------------------------
__global__ __launch_bounds__(256) void rope_kernel(float* __restrict__ q,
                                                   float* __restrict__ k) {
  const int QP = T_DIM * H_NUM * 32;   // 1048576
  const int KP = T_DIM * HKV_NUM * 32; // 262144
  int idx = blockIdx.x * 256 + threadIdx.x;
  float* base;
  int t, j;
  if (idx < QP) {
    t = idx >> 9;                 // /(16*32)
    int rem = idx & 511;
    base = q + (size_t)t * 1024 + (rem >> 5) * 64;
    j = rem & 31;
  } else {
    int i2 = idx - QP;
    if (i2 >= KP) return;
    t = i2 >> 7;                  // /(4*32)
    int rem = i2 & 127;
    base = k + (size_t)t * 256 + (rem >> 5) * 64;
    j = rem & 31;
  }
  // inv_freq = 10000^(-j/32) = exp(-j * ln(10000)/32)
  float inv = expf(-0.28782313662425575f * (float)j);
  float fr = (float)t * inv;
  float c = cosf(fr), s = sinf(fr);
  float a = base[j], b = base[j + 32];
  base[j] = a * c - b * s;
  base[j + 32] = b * c + a * s;
}

// ---------------------------------------------------------------------------
// Per-head scan: lac[t,h] = cumsum_t log_sigmoid(g), insc = sigmoid(-g).
// One block per head; 256 threads x 8 t each, Hillis-Steele block scan.
// ---------------------------------------------------------------------------
__global__ __launch_bounds__(256) void gate_scan_kernel(
    const float* __restrict__ g, float* __restrict__ lac,
    float* __restrict__ insc) {
  const int h = blockIdx.x;
  const int tid = threadIdx.x;
  __shared__ float part[256];
  float vals[8];
  float local = 0.f;
#pragma unroll
  for (int i = 0; i < 8; ++i) {
    int t = tid * 8 + i;
    float gv = g[t * 16 + h];
    // stable log_sigmoid
    float la = (gv > 0.f) ? -log1pf(expf(-gv)) : (gv - log1pf(expf(gv)));
    insc[t * 16 + h] = 1.f / (1.f + expf(gv));  // sigmoid(-g)
    vals[i] = la;
    local += la;
  }
  part[tid] = local;
  __syncthreads();
  for (int off = 1; off < 256; off <<= 1) {
    float add = (tid >= off) ? part[tid - off] : 0.f;
    __syncthreads();
    part[tid] += add;
    __syncthreads();
  }
  float run = (tid > 0) ? part[tid - 1] : 0.f;
#pragma unroll
  for (int i = 0; i < 8; ++i) {
    run += vals[i];
    lac[(tid * 8 + i) * 16 + h] = run;
  }
}

// ---------------------------------------------------------------------------
// Global decayed attention.
// y[t, h*64+d] += sum_{s<=t} exp(lac[t]-lac[s]) * insc[s] * (q_t . k_s) * v[s,d]
// Grid (slot 0..15, h 0..15, par 0..1). Each block does t-tiles {slot, 31-slot}
// (balanced s-tile count across the pair) and s-tiles of parity `par`
// (atomicAdd merges the two parities). 64x64 tiles, 4x4 register micro-tile.
// ---------------------------------------------------------------------------
__global__ __launch_bounds__(256) void global_attn_kernel(
    const float* __restrict__ q, const float* __restrict__ k,
    const float* __restrict__ v, const float* __restrict__ lac,
    const float* __restrict__ insc, float* __restrict__ y) {
  const int slot = blockIdx.x;
  const int h = blockIdx.y;
  const int par = blockIdx.z;
  const int kh = h >> 2;
  __shared__ float qs[64][65], ks[64][65], vs[64][65], ss[64][65];
  __shared__ float lacq[64], lacs[64], inss[64];
  const int tid = threadIdx.x;
  const int tx = tid & 15, ty = tid >> 4;
  for (int rep = 0; rep < 2; ++rep) {
    const int tt = rep ? (31 - slot) : slot;
    __syncthreads();
    for (int i = tid; i < 64 * 64; i += 256) {
      int r = i >> 6, c = i & 63;
      qs[r][c] = q[(size_t)(tt * 64 + r) * 1024 + h * 64 + c];
    }
    if (tid < 64) lacq[tid] = lac[(tt * 64 + tid) * 16 + h];
    float acc[4][4] = {};
    for (int st = par; st <= tt; st += 2) {
      __syncthreads();
      for (int i = tid; i < 64 * 64; i += 256) {
        int r = i >> 6, c = i & 63;
        ks[r][c] = k[(size_t)(st * 64 + r) * 256 + kh * 64 + c];
        vs[r][c] = v[(size_t)(st * 64 + r) * 256 + kh * 64 + c];
      }
      if (tid < 64) {
        lacs[tid] = lac[(st * 64 + tid) * 16 + h];
        inss[tid] = insc[(st * 64 + tid) * 16 + h];
      }
      __syncthreads();
      // phase 1: scores tile = q_tile @ k_tile^T
      float sc[4][4] = {};
#pragma unroll 4
      for (int c = 0; c < 64; ++c) {
        float a[4], b[4];
#pragma unroll
        for (int i = 0; i < 4; ++i) a[i] = qs[ty * 4 + i][c];
#pragma unroll
        for (int j = 0; j < 4; ++j) b[j] = ks[tx * 4 + j][c];
#pragma unroll
        for (int i = 0; i < 4; ++i)
#pragma unroll
          for (int j = 0; j < 4; ++j) sc[i][j] = fmaf(a[i], b[j], sc[i][j]);
      }
      const bool diag = (st == tt);
#pragma unroll
      for (int i = 0; i < 4; ++i) {
        const int r = ty * 4 + i;
#pragma unroll
        for (int j = 0; j < 4; ++j) {
          const int s = tx * 4 + j;
          // clamp the discarded (masked) exponent so no inf is ever computed
          float d = lacq[r] - lacs[s];
          float w = (diag && s > r) ? 0.f : expf(fminf(d, 0.f)) * inss[s];
          ss[r][s] = sc[i][j] * w;
        }
      }
      __syncthreads();
      // phase 2: acc += decayed_scores @ v_tile
#pragma unroll 4
      for (int s = 0; s < 64; ++s) {
        float a[4], b[4];
#pragma unroll
        for (int i = 0; i < 4; ++i) a[i] = ss[ty * 4 + i][s];
#pragma unroll
        for (int j = 0; j < 4; ++j) b[j] = vs[s][tx * 4 + j];
#pragma unroll
        for (int i = 0; i < 4; ++i)
#pragma unroll
          for (int j = 0; j < 4; ++j) acc[i][j] = fmaf(a[i], b[j], acc[i][j]);
      }
    }
#pragma unroll
    for (int i = 0; i < 4; ++i)
#pragma unroll
      for (int j = 0; j < 4; ++j)
        atomicAdd(&y[(size_t)(tt * 64 + ty * 4 + i) * 1024 + h * 64 + tx * 4 + j],
                  acc[i][j]);
  }
}

// ---------------------------------------------------------------------------
// Local windowed causal softmax attention (WIN=128), adds into y.
// Grid (wb*2+half 0..31, h 0..15). Block = 64 query rows (half window),
// keys/values = first s_len = (half+1)*64 rows of the window.
// ---------------------------------------------------------------------------
__global__ __launch_bounds__(256) void local_attn_kernel(
    const float* __restrict__ q, const float* __restrict__ k,
    const float* __restrict__ v, float* __restrict__ y) {
  const int wb = blockIdx.x >> 1;
  const int half = blockIdx.x & 1;
  const int h = blockIdx.y;
  const int kh = h >> 2;
  const int s_len = (half + 1) * 64;
  const int t0 = wb * 128;
  __shared__ float qs[64][65], ks[128][65], vs[128][65];
  __shared__ float ss[64][129];
  __shared__ float red[64][5];
  __shared__ float rmax[64], rsum[64];
  const int tid = threadIdx.x;
  const int tx = tid & 15, ty = tid >> 4;
  for (int i = tid; i < 64 * 64; i += 256) {
    int r = i >> 6, c = i & 63;
    qs[r][c] = q[(size_t)(t0 + half * 64 + r) * 1024 + h * 64 + c];
  }
  for (int i = tid; i < s_len * 64; i += 256) {
    int r = i >> 6, c = i & 63;
    ks[r][c] = k[(size_t)(t0 + r) * 256 + kh * 64 + c];
    vs[r][c] = v[(size_t)(t0 + r) * 256 + kh * 64 + c];
  }
  __syncthreads();
  // phase 1: scores (rows 64) x (s 128); thread = 4 rows x 8 s
  float sc[4][8] = {};
  if (tx * 8 < s_len) {
#pragma unroll 2
    for (int c = 0; c < 64; ++c) {
      float a[4], b[8];
#pragma unroll
      for (int i = 0; i < 4; ++i) a[i] = qs[ty * 4 + i][c];
#pragma unroll
      for (int j = 0; j < 8; ++j) b[j] = ks[tx * 8 + j][c];
#pragma unroll
      for (int i = 0; i < 4; ++i)
#pragma unroll
        for (int j = 0; j < 8; ++j) sc[i][j] = fmaf(a[i], b[j], sc[i][j]);
    }
  }
#pragma unroll
  for (int i = 0; i < 4; ++i) {
    const int r = ty * 4 + i;
    const int rg = half * 64 + r;  // row index within window
#pragma unroll
    for (int j = 0; j < 8; ++j) {
      const int s = tx * 8 + j;
      ss[r][s] = (s <= rg && s < s_len) ? sc[i][j] * 0.125f : -1e30f;
    }
  }
  __syncthreads();
  // softmax over s (rowwise): 4 threads per row
  {
    const int r = tid >> 2, sub = tid & 3;
    float m = -1e30f;
    for (int s = sub * 32; s < sub * 32 + 32; ++s) m = fmaxf(m, ss[r][s]);
    red[r][sub] = m;
    __syncthreads();
    if (sub == 0)
      rmax[r] = fmaxf(fmaxf(red[r][0], red[r][1]), fmaxf(red[r][2], red[r][3]));
    __syncthreads();
    const float rm = rmax[r];
    float psum = 0.f;
    for (int s = sub * 32; s < sub * 32 + 32; ++s) {
      float e = expf(ss[r][s] - rm);
      ss[r][s] = e;
      psum += e;
    }
    red[r][sub] = psum;
    __syncthreads();
    if (sub == 0) rsum[r] = red[r][0] + red[r][1] + red[r][2] + red[r][3];
    __syncthreads();
  }
  // phase 2: P @ v ; thread = 4 rows x 4 dims
  float acc[4][4] = {};
  for (int s = 0; s < s_len; ++s) {
    float a[4], b[4];
#pragma unroll
    for (int i = 0; i < 4; ++i) a[i] = ss[ty * 4 + i][s];
#pragma unroll
    for (int j = 0; j < 4; ++j) b[j] = vs[s][tx * 4 + j];
#pragma unroll
    for (int i = 0; i < 4; ++i)
#pragma unroll
      for (int j = 0; j < 4; ++j) acc[i][j] = fmaf(a[i], b[j], acc[i][j]);
  }
#pragma unroll
  for (int i = 0; i < 4; ++i) {
    const int r = ty * 4 + i;
    const float inv = 1.f / rsum[r];
#pragma unroll
    for (int j = 0; j < 4; ++j)
      atomicAdd(&y[(size_t)(t0 + half * 64 + r) * 1024 + h * 64 + tx * 4 + j],
                acc[i][j] * inv);
  }
}

// ---------------------------------------------------------------------------
// RMSNorm: yn[t,c] = y[t,c] * rsqrt(mean_c(y^2)+eps) * w[c]  (fp32 out)
// ---------------------------------------------------------------------------
__global__ __launch_bounds__(256) void rmsnorm_kernel(
    const float* __restrict__ y, const float* __restrict__ w,
    float* __restrict__ yn) {
  const int t = blockIdx.x;
  const int tid = threadIdx.x;
  __shared__ float red[4];
  __shared__ float scale_sh;
  float ssum = 0.f;
  for (int c = tid; c < 1024; c += 256) {
    float vv = y[(size_t)t * 1024 + c];
    ssum = fmaf(vv, vv, ssum);
  }
  for (int off = 32; off > 0; off >>= 1) ssum += __shfl_down(ssum, off, 64);
  const int lane = tid & 63, wid = tid >> 6;
  if (lane == 0) red[wid] = ssum;
  __syncthreads();
  if (tid == 0)
    scale_sh = rsqrtf((red[0] + red[1] + red[2] + red[3]) * (1.0f / 1024.0f) +
                      1e-5f);
  __syncthreads();
  const float scale = scale_sh;
  for (int c = tid; c < 1024; c += 256)
    yn[(size_t)t * 1024 + c] = y[(size_t)t * 1024 + c] * scale * w[c];
}

// ---------------------------------------------------------------------------
extern "C" void kernel_launch(void* const* d_in, const int* in_sizes, int n_in,
                              void* d_out, int out_size, void* d_ws,
                              size_t ws_size, hipStream_t stream) {
  const float* x = (const float*)d_in[0];
  const float* Wq = (const float*)d_in[1];
  const float* Wk = (const float*)d_in[2];
  const float* Wv = (const float*)d_in[3];
  const float* Wc = (const float*)d_in[4];
  const float* Wg = (const float*)d_in[5];
  const float* bg = (const float*)d_in[6];
  const float* rmsw = (const float*)d_in[7];
  float* out = (float*)d_out;

  float* qw = (float*)d_ws;               // 2048*1024 f32
  float* kw = qw + 2048 * 1024;           // 2048*256  f32
  float* vw = kw + 2048 * 256;            // 2048*256  f32
  float* gw = vw + 2048 * 256;            // 2048*16   f32
  float* lacw = gw + 2048 * 16;           // 2048*16   f32
  float* inscw = lacw + 2048 * 16;        // 2048*16   f32
  float* yw = inscw + 2048 * 16;          // 2048*1024 f32
  float* ynw = yw + 2048 * 1024;          // 2048*1024 f32
  // total ws usage ~28.5 MB

  gemm_kernel<<<dim3(16, 32), 256, 0, stream>>>(x, Wq, qw, 2048, 1024, 1024);
  gemm_kernel<<<dim3(4, 32), 256, 0, stream>>>(x, Wk, kw, 2048, 256, 1024);
  gemm_kernel<<<dim3(4, 32), 256, 0, stream>>>(x, Wv, vw, 2048, 256, 1024);
  gate_kernel<<<dim3(128), 256, 0, stream>>>(x, Wg, bg, gw);
  rope_kernel<<<dim3(5120), 256, 0, stream>>>(qw, kw);
  gate_scan_kernel<<<dim3(16), 256, 0, stream>>>(gw, lacw, inscw);
  hipMemsetAsync(yw, 0, (size_t)2048 * 1024 * sizeof(float), stream);
  global_attn_kernel<<<dim3(16, 16, 2), 256, 0, stream>>>(qw, kw, vw, lacw, inscw, yw);
  local_attn_kernel<<<dim3(32, 16), 256, 0, stream>>>(qw, kw, vw, yw);
  rmsnorm_kernel<<<dim3(2048), 256, 0, stream>>>(yw, rmsw, ynw);
  gemm_kernel<<<dim3(16, 32), 256, 0, stream>>>(ynw, Wc, out, 2048, 1024, 1024);
}

// Round 4
// 246.187 us; speedup vs baseline: 2.5842x; 2.5842x over previous
//
#include <hip/hip_runtime.h>
#include <hip/hip_bf16.h>

// Dtype contract (established rounds 0-3): ALL inputs fp32, OUTPUT fp32
// (harness compares in bf16 domain, threshold ~2% of max => bf16 MFMA is safe).
// Dims: B=1, T=2048, C=1024, H=16, HKV=4, DH=64, WIN=128.
// This round: all matmuls on bf16 MFMA 16x16x32 (fragment layouts per guide
// m89/m120; 16B-chunk XOR swizzle in LDS keeps ds_read_b128 <=2-way).

typedef __attribute__((ext_vector_type(8))) short bf16x8;  // 8 bf16 = 4 VGPR
typedef __attribute__((ext_vector_type(4))) float f32x4;

#define MFMA16(a, b, c) __builtin_amdgcn_mfma_f32_16x16x32_bf16(a, b, c, 0, 0, 0)
#define LN10000_OVER_32 0.28782313662425575f

__device__ __forceinline__ short f2b(float f) {
  __hip_bfloat16 h = __float2bfloat16(f);
  return *reinterpret_cast<short*>(&h);
}
__device__ __forceinline__ float b2f(short s) {
  return __uint_as_float(((unsigned)(unsigned short)s) << 16);
}

// ---------------------------------------------------------------------------
// fp32 -> bf16 elementwise (8 elts/thread)
// ---------------------------------------------------------------------------
__global__ __launch_bounds__(256) void cvt_f32_bf16(
    const float* __restrict__ src, short* __restrict__ dst, int n) {
  int i = (blockIdx.x * 256 + threadIdx.x) * 8;
  if (i >= n) return;
  float4 a = *(const float4*)(src + i);
  float4 b = *(const float4*)(src + i + 4);
  alignas(16) short o[8] = {f2b(a.x), f2b(a.y), f2b(a.z), f2b(a.w),
                            f2b(b.x), f2b(b.y), f2b(b.z), f2b(b.w)};
  *(float4*)(dst + i) = *(float4*)o;
}

// ---------------------------------------------------------------------------
// Transpose fp32 [R][C] -> bf16 [C][R].  grid (C/32, R/32), 256 thr.
// ---------------------------------------------------------------------------
__global__ __launch_bounds__(256) void transpose_cvt(
    const float* __restrict__ src, short* __restrict__ dst, int R, int C) {
  __shared__ float ts[32][33];
  int c0 = blockIdx.x * 32, r0 = blockIdx.y * 32;
  int tr = threadIdx.x >> 3, tc = (threadIdx.x & 7) * 4;
  float4 v = *(const float4*)&src[(size_t)(r0 + tr) * C + c0 + tc];
  ts[tr][tc] = v.x; ts[tr][tc + 1] = v.y; ts[tr][tc + 2] = v.z; ts[tr][tc + 3] = v.w;
  __syncthreads();
  alignas(8) short o[4];
#pragma unroll
  for (int i = 0; i < 4; ++i) o[i] = f2b(ts[tc + i][tr]);
  *(uint2*)&dst[(size_t)(c0 + tr) * R + r0 + tc] = *(uint2*)o;
}

// ---------------------------------------------------------------------------
// Transpose bf16 [R rows, ld stride] -> bf16 [C][R].  grid (C/32, R/32).
// ---------------------------------------------------------------------------
__global__ __launch_bounds__(256) void transpose_b16(
    const short* __restrict__ src, int ld, short* __restrict__ dst, int R, int C) {
  __shared__ short ts[32][40];
  int c0 = blockIdx.x * 32, r0 = blockIdx.y * 32;
  int tr = threadIdx.x >> 3, tc = (threadIdx.x & 7) * 4;
  *(uint2*)&ts[tr][tc] = *(const uint2*)&src[(size_t)(r0 + tr) * ld + c0 + tc];
  __syncthreads();
  alignas(8) short o[4] = {ts[tc][tr], ts[tc + 1][tr], ts[tc + 2][tr], ts[tc + 3][tr]};
  *(uint2*)&dst[(size_t)(c0 + tr) * R + r0 + tc] = *(uint2*)o;
}

// ---------------------------------------------------------------------------
// MFMA GEMM: C[M,N] = A[M,K] @ Bt[N,K]^T, bf16 in, fp32 acc.
// 128x128 tile, BK=64, 4 waves 2x2 (64x64 each), 4x4 MFMA tiles/wave.
// LDS 16B-chunk xor swizzle: chunk(row,c16) at (row*8 + (c16^(row&7)))*8.
// ROPE: heads (col/64) < 20 get rotary applied in epilogue (q + k heads).
// ---------------------------------------------------------------------------
template <bool ROPE, bool OUT_BF16>
__global__ __launch_bounds__(256) void gemm_mfma(
    const short* __restrict__ A, const short* __restrict__ Bt,
    void* __restrict__ Cout, int M, int N, int K) {
  __shared__ short As[128 * 64];
  __shared__ short Bs[128 * 64];
  const int tid = threadIdx.x;
  const int lane = tid & 63, wid = tid >> 6;
  const int wm = wid >> 1, wn = wid & 1;
  const int m0 = blockIdx.y * 128, n0 = blockIdx.x * 128;
  const int l15 = lane & 15, lq = lane >> 4;
  f32x4 acc[4][4];
#pragma unroll
  for (int i = 0; i < 4; ++i)
#pragma unroll
    for (int j = 0; j < 4; ++j) acc[i][j] = {0.f, 0.f, 0.f, 0.f};
  for (int kt = 0; kt < K; kt += 64) {
    __syncthreads();
#pragma unroll
    for (int i = 0; i < 4; ++i) {
      int c = tid + 256 * i;
      int row = c >> 3, cc = c & 7;
      int sw = (row * 8 + (cc ^ (row & 7))) * 8;
      *(float4*)&As[sw] = *(const float4*)&A[(size_t)(m0 + row) * K + kt + cc * 8];
      *(float4*)&Bs[sw] = *(const float4*)&Bt[(size_t)(n0 + row) * K + kt + cc * 8];
    }
    __syncthreads();
    bf16x8 af[4][2], bfr[4][2];
#pragma unroll
    for (int t = 0; t < 4; ++t)
#pragma unroll
      for (int ks = 0; ks < 2; ++ks) {
        int c16 = ks * 4 + lq;
        int ar = wm * 64 + t * 16 + l15;
        af[t][ks] = *(const bf16x8*)&As[(ar * 8 + (c16 ^ (ar & 7))) * 8];
        int br = wn * 64 + t * 16 + l15;
        bfr[t][ks] = *(const bf16x8*)&Bs[(br * 8 + (c16 ^ (br & 7))) * 8];
      }
#pragma unroll
    for (int mt = 0; mt < 4; ++mt)
#pragma unroll
      for (int nt = 0; nt < 4; ++nt) {
        acc[mt][nt] = MFMA16(af[mt][0], bfr[nt][0], acc[mt][nt]);
        acc[mt][nt] = MFMA16(af[mt][1], bfr[nt][1], acc[mt][nt]);
      }
  }
  const int head = (n0 + wn * 64) >> 6;
  const bool do_rope = ROPE && (head < 20);
#pragma unroll
  for (int mt = 0; mt < 4; ++mt)
#pragma unroll
    for (int r = 0; r < 4; ++r) {
      int row_g = m0 + wm * 64 + mt * 16 + lq * 4 + r;  // C/D: row=(lane>>4)*4+reg
      if (OUT_BF16) {
        short* C = (short*)Cout;
        if (do_rope) {
          float t = (float)row_g;
#pragma unroll
          for (int nt = 0; nt < 2; ++nt) {
            int d = nt * 16 + l15;  // 0..31
            float ivf = __expf(-LN10000_OVER_32 * (float)d);
            float th = t * ivf;
            float cs = cosf(th), sn = sinf(th);
            float a = acc[mt][nt][r], b = acc[mt][nt + 2][r];
            int colg = n0 + wn * 64 + nt * 16 + l15;
            C[(size_t)row_g * N + colg] = f2b(a * cs - b * sn);
            C[(size_t)row_g * N + colg + 32] = f2b(b * cs + a * sn);
          }
        } else {
#pragma unroll
          for (int nt = 0; nt < 4; ++nt) {
            int colg = n0 + wn * 64 + nt * 16 + l15;
            C[(size_t)row_g * N + colg] = f2b(acc[mt][nt][r]);
          }
        }
      } else {
        float* C = (float*)Cout;
#pragma unroll
        for (int nt = 0; nt < 4; ++nt) {
          int colg = n0 + wn * 64 + nt * 16 + l15;
          C[(size_t)row_g * N + colg] = acc[mt][nt][r];
        }
      }
    }
}

// ---------------------------------------------------------------------------
// Gate logits: g[t,h] = x[t,:] @ Wg[:,h] + bg[h]
// ---------------------------------------------------------------------------
__global__ __launch_bounds__(256) void gate_kernel(
    const float* __restrict__ x, const float* __restrict__ Wg,
    const float* __restrict__ bg, float* __restrict__ g) {
  int idx = blockIdx.x * 256 + threadIdx.x;
  int t = idx >> 4, h = idx & 15;
  const float* xr = x + (size_t)t * 1024;
  float acc = 0.f;
  for (int c = 0; c < 1024; c += 4) {
    float4 xv = *(const float4*)(xr + c);
    acc = fmaf(xv.x, Wg[(c + 0) * 16 + h], acc);
    acc = fmaf(xv.y, Wg[(c + 1) * 16 + h], acc);
    acc = fmaf(xv.z, Wg[(c + 2) * 16 + h], acc);
    acc = fmaf(xv.w, Wg[(c + 3) * 16 + h], acc);
  }
  g[idx] = acc + bg[h];
}

// ---------------------------------------------------------------------------
// Per-head inclusive scan of log_sigmoid(g); outputs HEAD-MAJOR [16][2048].
// ---------------------------------------------------------------------------
__global__ __launch_bounds__(256) void gate_scan_kernel(
    const float* __restrict__ g, float* __restrict__ lac,
    float* __restrict__ insc) {
  const int h = blockIdx.x;
  const int tid = threadIdx.x;
  __shared__ float part[256];
  float vals[8];
  float local = 0.f;
#pragma unroll
  for (int i = 0; i < 8; ++i) {
    int t = tid * 8 + i;
    float gv = g[t * 16 + h];
    float la = (gv > 0.f) ? -log1pf(expf(-gv)) : (gv - log1pf(expf(gv)));
    insc[h * 2048 + t] = 1.f / (1.f + expf(gv));
    vals[i] = la;
    local += la;
  }
  part[tid] = local;
  __syncthreads();
  for (int off = 1; off < 256; off <<= 1) {
    float add = (tid >= off) ? part[tid - off] : 0.f;
    __syncthreads();
    part[tid] += add;
    __syncthreads();
  }
  float run = (tid > 0) ? part[tid - 1] : 0.f;
#pragma unroll
  for (int i = 0; i < 8; ++i) {
    run += vals[i];
    lac[h * 2048 + tid * 8 + i] = run;
  }
}

// ---------------------------------------------------------------------------
// Global decayed attention, MFMA. Grid (slot 16, h 16, par 2).
// Block handles t-tiles {slot, 31-slot}; s-tiles of parity par.
// Writes partial O (bf16) to y0/y1 (summed in rmsnorm).
// qkv rows: [q(1024) | k(256) | v(256)], vtb = v^T [256][2048].
// ---------------------------------------------------------------------------
__global__ __launch_bounds__(256) void global_attn_mfma(
    const short* __restrict__ qkv, const short* __restrict__ vtb,
    const float* __restrict__ lac, const float* __restrict__ insc,
    short* __restrict__ y0, short* __restrict__ y1) {
  const int slot = blockIdx.x, h = blockIdx.y, par = blockIdx.z;
  const int kh = h >> 2;
  __shared__ short Qs[64 * 64], Ks[64 * 64], Vts[64 * 64], Ps[64 * 64];
  __shared__ float lacq[64], lacs[64], inss[64];
  const int tid = threadIdx.x, lane = tid & 63, wid = tid >> 6;
  const int l15 = lane & 15, lq = lane >> 4;
  short* yout = par ? y1 : y0;
  for (int rep = 0; rep < 2; ++rep) {
    const int tt = rep ? 31 - slot : slot;
    __syncthreads();
#pragma unroll
    for (int i = 0; i < 2; ++i) {
      int c = tid + 256 * i;
      int row = c >> 3, cc = c & 7;
      *(float4*)&Qs[(row * 8 + (cc ^ (row & 7))) * 8] =
          *(const float4*)&qkv[(size_t)(tt * 64 + row) * 1536 + h * 64 + cc * 8];
    }
    if (tid < 64) lacq[tid] = lac[h * 2048 + tt * 64 + tid];
    f32x4 o[4];
#pragma unroll
    for (int nt = 0; nt < 4; ++nt) o[nt] = {0.f, 0.f, 0.f, 0.f};
    for (int st = par; st <= tt; st += 2) {
      __syncthreads();
#pragma unroll
      for (int i = 0; i < 2; ++i) {
        int c = tid + 256 * i;
        int row = c >> 3, cc = c & 7;
        int sw = (row * 8 + (cc ^ (row & 7))) * 8;
        *(float4*)&Ks[sw] =
            *(const float4*)&qkv[(size_t)(st * 64 + row) * 1536 + 1024 + kh * 64 + cc * 8];
        *(float4*)&Vts[sw] =
            *(const float4*)&vtb[(size_t)(kh * 64 + row) * 2048 + st * 64 + cc * 8];
      }
      if (tid < 64) {
        lacs[tid] = lac[h * 2048 + st * 64 + tid];
        inss[tid] = insc[h * 2048 + st * 64 + tid];
      }
      __syncthreads();
      // S = Q @ K^T  (wave strip: rows wid*16..+15)
      const int qr = wid * 16 + l15;
      bf16x8 aq[2];
#pragma unroll
      for (int ks = 0; ks < 2; ++ks) {
        int c16 = ks * 4 + lq;
        aq[ks] = *(const bf16x8*)&Qs[(qr * 8 + (c16 ^ (qr & 7))) * 8];
      }
      f32x4 sv[4];
#pragma unroll
      for (int nt = 0; nt < 4; ++nt) {
        int kr = nt * 16 + l15;
        bf16x8 bk0 = *(const bf16x8*)&Ks[(kr * 8 + ((0 + lq) ^ (kr & 7))) * 8];
        bf16x8 bk1 = *(const bf16x8*)&Ks[(kr * 8 + ((4 + lq) ^ (kr & 7))) * 8];
        f32x4 z = {0.f, 0.f, 0.f, 0.f};
        z = MFMA16(aq[0], bk0, z);
        z = MFMA16(aq[1], bk1, z);
        sv[nt] = z;
      }
      // decay/mask -> P (bf16, swizzled)
      const bool diag = (st == tt);
#pragma unroll
      for (int nt = 0; nt < 4; ++nt) {
        int col = nt * 16 + l15;
        float ls = lacs[col], is = inss[col];
#pragma unroll
        for (int r = 0; r < 4; ++r) {
          int row = wid * 16 + lq * 4 + r;
          float d = lacq[row] - ls;
          float w = __expf(fminf(d, 0.f)) * is;
          if (diag && col > row) w = 0.f;
          Ps[(row * 8 + ((col >> 3) ^ (row & 7))) * 8 + (col & 7)] = f2b(sv[nt][r] * w);
        }
      }
      __syncthreads();
      // O += P @ V   (Vt layout [d][s])
      bf16x8 ap[2];
#pragma unroll
      for (int ks = 0; ks < 2; ++ks) {
        int c16 = ks * 4 + lq;
        ap[ks] = *(const bf16x8*)&Ps[(qr * 8 + (c16 ^ (qr & 7))) * 8];
      }
#pragma unroll
      for (int nt = 0; nt < 4; ++nt) {
        int vr = nt * 16 + l15;
        bf16x8 bv0 = *(const bf16x8*)&Vts[(vr * 8 + ((0 + lq) ^ (vr & 7))) * 8];
        bf16x8 bv1 = *(const bf16x8*)&Vts[(vr * 8 + ((4 + lq) ^ (vr & 7))) * 8];
        o[nt] = MFMA16(ap[0], bv0, o[nt]);
        o[nt] = MFMA16(ap[1], bv1, o[nt]);
      }
    }
#pragma unroll
    for (int nt = 0; nt < 4; ++nt)
#pragma unroll
      for (int r = 0; r < 4; ++r) {
        int row_g = tt * 64 + wid * 16 + lq * 4 + r;
        int colg = h * 64 + nt * 16 + l15;
        yout[(size_t)row_g * 1024 + colg] = f2b(o[nt][r]);
      }
  }
}

// ---------------------------------------------------------------------------
// Local windowed softmax attention, MFMA. Grid (32 q-strips, 16 h).
// Row softmax via 16-lane shuffle reduction (rows live across lanes with
// equal lane>>4). Writes ylocal bf16 (summed in rmsnorm).
// ---------------------------------------------------------------------------
__global__ __launch_bounds__(256) void local_attn_mfma(
    const short* __restrict__ qkv, const short* __restrict__ vtb,
    short* __restrict__ yl) {
  const int half = blockIdx.x & 1, wb = blockIdx.x >> 1, h = blockIdx.y;
  const int kh = h >> 2, t0 = wb * 128;
  __shared__ short Qs[64 * 64];
  __shared__ short Ks[128 * 64];
  __shared__ short Vts[64 * 128];  // [d][s], 16 chunks/row
  __shared__ short Ps[64 * 128];
  const int tid = threadIdx.x, lane = tid & 63, wid = tid >> 6;
  const int l15 = lane & 15, lq = lane >> 4;
#pragma unroll
  for (int i = 0; i < 2; ++i) {
    int c = tid + 256 * i;
    int row = c >> 3, cc = c & 7;
    *(float4*)&Qs[(row * 8 + (cc ^ (row & 7))) * 8] =
        *(const float4*)&qkv[(size_t)(t0 + half * 64 + row) * 1536 + h * 64 + cc * 8];
  }
#pragma unroll
  for (int i = 0; i < 4; ++i) {
    int c = tid + 256 * i;
    int row = c >> 3, cc = c & 7;
    *(float4*)&Ks[(row * 8 + (cc ^ (row & 7))) * 8] =
        *(const float4*)&qkv[(size_t)(t0 + row) * 1536 + 1024 + kh * 64 + cc * 8];
  }
#pragma unroll
  for (int i = 0; i < 4; ++i) {
    int c = tid + 256 * i;
    int row = c >> 4, cc = c & 15;
    int sw = (row * 16 + ((cc & 8) | ((cc & 7) ^ (row & 7)))) * 8;
    *(float4*)&Vts[sw] = *(const float4*)&vtb[(size_t)(kh * 64 + row) * 2048 + t0 + cc * 8];
  }
  __syncthreads();
  const int qr = wid * 16 + l15;
  bf16x8 aq[2];
#pragma unroll
  for (int ks = 0; ks < 2; ++ks) {
    int c16 = ks * 4 + lq;
    aq[ks] = *(const bf16x8*)&Qs[(qr * 8 + (c16 ^ (qr & 7))) * 8];
  }
  f32x4 sv[2][4];
  const int nst = half + 1;
  for (int st = 0; st < nst; ++st)
#pragma unroll
    for (int nt = 0; nt < 4; ++nt) {
      int kr = st * 64 + nt * 16 + l15;
      bf16x8 bk0 = *(const bf16x8*)&Ks[(kr * 8 + ((0 + lq) ^ (kr & 7))) * 8];
      bf16x8 bk1 = *(const bf16x8*)&Ks[(kr * 8 + ((4 + lq) ^ (kr & 7))) * 8];
      f32x4 z = {0.f, 0.f, 0.f, 0.f};
      z = MFMA16(aq[0], bk0, z);
      z = MFMA16(aq[1], bk1, z);
      sv[st][nt] = z;
    }
  // mask + scale (1/sqrt(64)=0.125), rowwise softmax
  float mrow[4], ssum[4];
#pragma unroll
  for (int r = 0; r < 4; ++r) mrow[r] = -1e30f;
  for (int st = 0; st < nst; ++st)
#pragma unroll
    for (int nt = 0; nt < 4; ++nt) {
      int col = st * 64 + nt * 16 + l15;
#pragma unroll
      for (int r = 0; r < 4; ++r) {
        int row = half * 64 + wid * 16 + lq * 4 + r;  // row within window
        float v = (col <= row) ? sv[st][nt][r] * 0.125f : -1e30f;
        sv[st][nt][r] = v;
        mrow[r] = fmaxf(mrow[r], v);
      }
    }
#pragma unroll
  for (int r = 0; r < 4; ++r) {
    for (int off = 1; off < 16; off <<= 1)
      mrow[r] = fmaxf(mrow[r], __shfl_xor(mrow[r], off, 64));
    ssum[r] = 0.f;
  }
  for (int st = 0; st < nst; ++st)
#pragma unroll
    for (int nt = 0; nt < 4; ++nt) {
      int col = st * 64 + nt * 16 + l15;
#pragma unroll
      for (int r = 0; r < 4; ++r) {
        float e = __expf(sv[st][nt][r] - mrow[r]);
        ssum[r] += e;
        int row = wid * 16 + lq * 4 + r;
        int c16 = col >> 3;
        Ps[(row * 16 + ((c16 & 8) | ((c16 & 7) ^ (row & 7)))) * 8 + (col & 7)] = f2b(e);
      }
    }
#pragma unroll
  for (int r = 0; r < 4; ++r) {
    for (int off = 1; off < 16; off <<= 1) ssum[r] += __shfl_xor(ssum[r], off, 64);
    ssum[r] = 1.f / ssum[r];
  }
  __syncthreads();
  f32x4 o[4];
#pragma unroll
  for (int nt = 0; nt < 4; ++nt) o[nt] = {0.f, 0.f, 0.f, 0.f};
  for (int ks = 0; ks < nst * 2; ++ks) {
    int c16 = ks * 4 + lq;
    bf16x8 ap = *(const bf16x8*)&Ps[(qr * 16 + ((c16 & 8) | ((c16 & 7) ^ (qr & 7)))) * 8];
#pragma unroll
    for (int nt = 0; nt < 4; ++nt) {
      int vr = nt * 16 + l15;
      bf16x8 bv = *(const bf16x8*)&Vts[(vr * 16 + ((c16 & 8) | ((c16 & 7) ^ (vr & 7)))) * 8];
      o[nt] = MFMA16(ap, bv, o[nt]);
    }
  }
#pragma unroll
  for (int nt = 0; nt < 4; ++nt)
#pragma unroll
    for (int r = 0; r < 4; ++r) {
      int row_g = t0 + half * 64 + wid * 16 + lq * 4 + r;
      int colg = h * 64 + nt * 16 + l15;
      yl[(size_t)row_g * 1024 + colg] = f2b(o[nt][r] * ssum[r]);
    }
}

// ---------------------------------------------------------------------------
// RMSNorm over y = y0 + y1 + ylocal (bf16 partials); writes yn bf16.
// ---------------------------------------------------------------------------
__global__ __launch_bounds__(256) void rmsnorm_fuse(
    const short* __restrict__ y0, const short* __restrict__ y1,
    const short* __restrict__ ylc, const float* __restrict__ w,
    short* __restrict__ yn) {
  const int t = blockIdx.x, tid = threadIdx.x;
  __shared__ float red[4];
  __shared__ float rowv[1024];
  __shared__ float scale_sh;
  float ssum = 0.f;
  for (int c = tid; c < 1024; c += 256) {
    size_t idx = (size_t)t * 1024 + c;
    float v = b2f(y0[idx]) + b2f(y1[idx]) + b2f(ylc[idx]);
    rowv[c] = v;
    ssum = fmaf(v, v, ssum);
  }
  for (int off = 32; off > 0; off >>= 1) ssum += __shfl_down(ssum, off, 64);
  const int lane = tid & 63, wd = tid >> 6;
  if (lane == 0) red[wd] = ssum;
  __syncthreads();
  if (tid == 0)
    scale_sh = rsqrtf((red[0] + red[1] + red[2] + red[3]) * (1.0f / 1024.0f) + 1e-5f);
  __syncthreads();
  const float scale = scale_sh;
  for (int c = tid; c < 1024; c += 256)
    yn[(size_t)t * 1024 + c] = f2b(rowv[c] * scale * w[c]);
}

// ---------------------------------------------------------------------------
extern "C" void kernel_launch(void* const* d_in, const int* in_sizes, int n_in,
                              void* d_out, int out_size, void* d_ws,
                              size_t ws_size, hipStream_t stream) {
  const float* x = (const float*)d_in[0];
  const float* Wq = (const float*)d_in[1];
  const float* Wk = (const float*)d_in[2];
  const float* Wv = (const float*)d_in[3];
  const float* Wc = (const float*)d_in[4];
  const float* Wg = (const float*)d_in[5];
  const float* bg = (const float*)d_in[6];
  const float* rmsw = (const float*)d_in[7];
  float* out = (float*)d_out;

  // ws layout (shorts unless noted); total ~29.8 MB (<= round-3's 29.9 MB use)
  short* wqkvT = (short*)d_ws;               // [1536][1024]
  short* wcT = wqkvT + 1536 * 1024;          // [1024][1024]
  short* qkvb = wcT + 1024 * 1024;           // [2048][1536]
  short* vtb = qkvb + 2048 * 1536;           // [256][2048]
  float* gw = (float*)(vtb + 256 * 2048);    // [2048][16]
  float* lacw = gw + 2048 * 16;              // [16][2048]
  float* inscw = lacw + 16 * 2048;           // [16][2048]
  short* xb = (short*)(inscw + 16 * 2048);   // [2048][1024]
  short* y0 = xb;                            // alias: xb dead after qkv GEMM
  short* y1 = xb + 2048 * 1024;
  short* ylc = y1 + 2048 * 1024;
  short* yn = ylc + 2048 * 1024;

  cvt_f32_bf16<<<1024, 256, 0, stream>>>(x, xb, 2048 * 1024);
  transpose_cvt<<<dim3(32, 32), 256, 0, stream>>>(Wq, wqkvT, 1024, 1024);
  transpose_cvt<<<dim3(8, 32), 256, 0, stream>>>(Wk, wqkvT + 1024 * 1024, 1024, 256);
  transpose_cvt<<<dim3(8, 32), 256, 0, stream>>>(Wv, wqkvT + 1280 * 1024, 1024, 256);
  transpose_cvt<<<dim3(32, 32), 256, 0, stream>>>(Wc, wcT, 1024, 1024);
  gate_kernel<<<128, 256, 0, stream>>>(x, Wg, bg, gw);
  gate_scan_kernel<<<16, 256, 0, stream>>>(gw, lacw, inscw);
  gemm_mfma<true, true><<<dim3(12, 16), 256, 0, stream>>>(xb, wqkvT, qkvb, 2048, 1536, 1024);
  transpose_b16<<<dim3(8, 64), 256, 0, stream>>>(qkvb + 1280, 1536, vtb, 2048, 256);
  global_attn_mfma<<<dim3(16, 16, 2), 256, 0, stream>>>(qkvb, vtb, lacw, inscw, y0, y1);
  local_attn_mfma<<<dim3(32, 16), 256, 0, stream>>>(qkvb, vtb, ylc);
  rmsnorm_fuse<<<2048, 256, 0, stream>>>(y0, y1, ylc, rmsw, yn);
  gemm_mfma<false, false><<<dim3(8, 16), 256, 0, stream>>>(yn, wcT, out, 2048, 1024, 1024);
}

// Round 5
// 187.594 us; speedup vs baseline: 3.3914x; 1.3123x over previous
//
#include <hip/hip_runtime.h>
#include <hip/hip_bf16.h>

// Dtype contract (established rounds 0-3): ALL inputs fp32, OUTPUT fp32
// (harness compares in bf16 domain, threshold ~2% of max => bf16 MFMA is safe).
// Dims: B=1, T=2048, C=1024, H=16, HKV=4, DH=64, WIN=128.
// Round 5: GEMMs rebuilt as 64x64-tile / 768- and 512-block kernels with
// async global_load_lds (width 16) staging and XCD-aware block swizzle.
// (Round-4 GEMMs were MLP-limited: 1 block/CU, ~800 GB/s delivery.)

typedef __attribute__((ext_vector_type(8))) short bf16x8;  // 8 bf16 = 4 VGPR
typedef __attribute__((ext_vector_type(4))) float f32x4;

#define MFMA16(a, b, c) __builtin_amdgcn_mfma_f32_16x16x32_bf16(a, b, c, 0, 0, 0)
#define LN10000_OVER_32 0.28782313662425575f

__device__ __forceinline__ short f2b(float f) {
  __hip_bfloat16 h = __float2bfloat16(f);
  return *reinterpret_cast<short*>(&h);
}
__device__ __forceinline__ float b2f(short s) {
  return __uint_as_float(((unsigned)(unsigned short)s) << 16);
}
// Async 16B/lane global->LDS copy. LDS dest = wave-uniform base + lane*16.
__device__ __forceinline__ void gload16(const void* g, void* l) {
  __builtin_amdgcn_global_load_lds(
      (const __attribute__((address_space(1))) void*)g,
      (__attribute__((address_space(3))) void*)l, 16, 0, 0);
}

// ---------------------------------------------------------------------------
// fp32 -> bf16 elementwise (8 elts/thread)
// ---------------------------------------------------------------------------
__global__ __launch_bounds__(256) void cvt_f32_bf16(
    const float* __restrict__ src, short* __restrict__ dst, int n) {
  int i = (blockIdx.x * 256 + threadIdx.x) * 8;
  if (i >= n) return;
  float4 a = *(const float4*)(src + i);
  float4 b = *(const float4*)(src + i + 4);
  alignas(16) short o[8] = {f2b(a.x), f2b(a.y), f2b(a.z), f2b(a.w),
                            f2b(b.x), f2b(b.y), f2b(b.z), f2b(b.w)};
  *(float4*)(dst + i) = *(float4*)o;
}

// ---------------------------------------------------------------------------
// Transpose fp32 [R][C] -> bf16 [C][R].  grid (C/32, R/32), 256 thr.
// ---------------------------------------------------------------------------
__global__ __launch_bounds__(256) void transpose_cvt(
    const float* __restrict__ src, short* __restrict__ dst, int R, int C) {
  __shared__ float ts[32][33];
  int c0 = blockIdx.x * 32, r0 = blockIdx.y * 32;
  int tr = threadIdx.x >> 3, tc = (threadIdx.x & 7) * 4;
  float4 v = *(const float4*)&src[(size_t)(r0 + tr) * C + c0 + tc];
  ts[tr][tc] = v.x; ts[tr][tc + 1] = v.y; ts[tr][tc + 2] = v.z; ts[tr][tc + 3] = v.w;
  __syncthreads();
  alignas(8) short o[4];
#pragma unroll
  for (int i = 0; i < 4; ++i) o[i] = f2b(ts[tc + i][tr]);
  *(uint2*)&dst[(size_t)(c0 + tr) * R + r0 + tc] = *(uint2*)o;
}

// ---------------------------------------------------------------------------
// Transpose bf16 [R rows, ld stride] -> bf16 [C][R].  grid (C/32, R/32).
// ---------------------------------------------------------------------------
__global__ __launch_bounds__(256) void transpose_b16(
    const short* __restrict__ src, int ld, short* __restrict__ dst, int R, int C) {
  __shared__ short ts[32][40];
  int c0 = blockIdx.x * 32, r0 = blockIdx.y * 32;
  int tr = threadIdx.x >> 3, tc = (threadIdx.x & 7) * 4;
  *(uint2*)&ts[tr][tc] = *(const uint2*)&src[(size_t)(r0 + tr) * ld + c0 + tc];
  __syncthreads();
  alignas(8) short o[4] = {ts[tc][tr], ts[tc + 1][tr], ts[tc + 2][tr], ts[tc + 3][tr]};
  *(uint2*)&dst[(size_t)(c0 + tr) * R + r0 + tc] = *(uint2*)o;
}

// ---------------------------------------------------------------------------
// MFMA GEMM: C[M,N] = A[M,K] @ Bt[N,K]^T, bf16 in, fp32 acc.
// 64x64 tile, BK=64, 4 waves stacked on M (16 rows x 64 cols each).
// Staging via global_load_lds: physical LDS chunk p=row*8+(c16^(row&7)).
// 1-D grid with XCD swizzle: blocks sharing an A row-strip (same by) get
// linear ids with equal id%8 -> same XCD under round-robin dispatch.
// ROPE: N-tiles (bx) < 20 get rotary applied in epilogue (q + k heads).
// ---------------------------------------------------------------------------
template <bool ROPE, bool OUT_BF16>
__global__ __launch_bounds__(256) void gemm_mfma(
    const short* __restrict__ A, const short* __restrict__ Bt,
    void* __restrict__ Cout, int M, int N, int K, int nbx) {
  __shared__ short As[64 * 64];
  __shared__ short Bs[64 * 64];
  const int tid = threadIdx.x, lane = tid & 63, wid = tid >> 6;
  const int l15 = lane & 15, lq = lane >> 4;
  const int id = blockIdx.x;
  const int jlin = id >> 3;
  const int by = (id & 7) + 8 * (jlin / nbx);
  const int bx = jlin % nbx;
  const int m0 = by * 64, n0 = bx * 64;
  const int srow = lane >> 3;          // 0..7 within an 8-row staging slab
  const int sc16 = (lane & 7) ^ srow;  // logical k-chunk for this lane
  f32x4 acc[4];
#pragma unroll
  for (int nt = 0; nt < 4; ++nt) acc[nt] = {0.f, 0.f, 0.f, 0.f};
  for (int kt = 0; kt < K; kt += 64) {
    __syncthreads();
#pragma unroll
    for (int i = 0; i < 2; ++i) {
      int jj = wid * 2 + i;          // staging slab 0..7
      int row = jj * 8 + srow;       // tile row 0..63 (row&7 == srow)
      gload16(A + (size_t)(m0 + row) * K + kt + sc16 * 8, &As[jj * 512]);
      gload16(Bt + (size_t)(n0 + row) * K + kt + sc16 * 8, &Bs[jj * 512]);
    }
    __syncthreads();  // drains vmcnt -> LDS tiles complete
    bf16x8 af[2], bfr[4][2];
#pragma unroll
    for (int ks = 0; ks < 2; ++ks) {
      int c16 = ks * 4 + lq;
      int ar = wid * 16 + l15;
      af[ks] = *(const bf16x8*)&As[(ar * 8 + (c16 ^ (ar & 7))) * 8];
#pragma unroll
      for (int nt = 0; nt < 4; ++nt) {
        int br = nt * 16 + l15;
        bfr[nt][ks] = *(const bf16x8*)&Bs[(br * 8 + (c16 ^ (br & 7))) * 8];
      }
    }
#pragma unroll
    for (int ks = 0; ks < 2; ++ks)
#pragma unroll
      for (int nt = 0; nt < 4; ++nt)
        acc[nt] = MFMA16(af[ks], bfr[nt][ks], acc[nt]);
  }
  const bool do_rope = ROPE && (bx < 20);
#pragma unroll
  for (int r = 0; r < 4; ++r) {
    int row_g = m0 + wid * 16 + lq * 4 + r;  // C/D: row=(lane>>4)*4+reg
    if (OUT_BF16) {
      short* C = (short*)Cout;
      if (do_rope) {
        float t = (float)row_g;
#pragma unroll
        for (int nt = 0; nt < 2; ++nt) {
          int d = nt * 16 + l15;  // 0..31
          float th = t * __expf(-LN10000_OVER_32 * (float)d);
          float cs = cosf(th), sn = sinf(th);
          float a = acc[nt][r], b = acc[nt + 2][r];
          C[(size_t)row_g * N + n0 + d] = f2b(a * cs - b * sn);
          C[(size_t)row_g * N + n0 + d + 32] = f2b(b * cs + a * sn);
        }
      } else {
#pragma unroll
        for (int nt = 0; nt < 4; ++nt)
          C[(size_t)row_g * N + n0 + nt * 16 + l15] = f2b(acc[nt][r]);
      }
    } else {
      float* C = (float*)Cout;
#pragma unroll
      for (int nt = 0; nt < 4; ++nt)
        C[(size_t)row_g * N + n0 + nt * 16 + l15] = acc[nt][r];
    }
  }
}

// ---------------------------------------------------------------------------
// Gate logits: g[t,h] = x[t,:] @ Wg[:,h] + bg[h]
// ---------------------------------------------------------------------------
__global__ __launch_bounds__(256) void gate_kernel(
    const float* __restrict__ x, const float* __restrict__ Wg,
    const float* __restrict__ bg, float* __restrict__ g) {
  int idx = blockIdx.x * 256 + threadIdx.x;
  int t = idx >> 4, h = idx & 15;
  const float* xr = x + (size_t)t * 1024;
  float acc = 0.f;
  for (int c = 0; c < 1024; c += 4) {
    float4 xv = *(const float4*)(xr + c);
    acc = fmaf(xv.x, Wg[(c + 0) * 16 + h], acc);
    acc = fmaf(xv.y, Wg[(c + 1) * 16 + h], acc);
    acc = fmaf(xv.z, Wg[(c + 2) * 16 + h], acc);
    acc = fmaf(xv.w, Wg[(c + 3) * 16 + h], acc);
  }
  g[idx] = acc + bg[h];
}

// ---------------------------------------------------------------------------
// Per-head inclusive scan of log_sigmoid(g); outputs HEAD-MAJOR [16][2048].
// ---------------------------------------------------------------------------
__global__ __launch_bounds__(256) void gate_scan_kernel(
    const float* __restrict__ g, float* __restrict__ lac,
    float* __restrict__ insc) {
  const int h = blockIdx.x;
  const int tid = threadIdx.x;
  __shared__ float part[256];
  float vals[8];
  float local = 0.f;
#pragma unroll
  for (int i = 0; i < 8; ++i) {
    int t = tid * 8 + i;
    float gv = g[t * 16 + h];
    float la = (gv > 0.f) ? -log1pf(expf(-gv)) : (gv - log1pf(expf(gv)));
    insc[h * 2048 + t] = 1.f / (1.f + expf(gv));
    vals[i] = la;
    local += la;
  }
  part[tid] = local;
  __syncthreads();
  for (int off = 1; off < 256; off <<= 1) {
    float add = (tid >= off) ? part[tid - off] : 0.f;
    __syncthreads();
    part[tid] += add;
    __syncthreads();
  }
  float run = (tid > 0) ? part[tid - 1] : 0.f;
#pragma unroll
  for (int i = 0; i < 8; ++i) {
    run += vals[i];
    lac[h * 2048 + tid * 8 + i] = run;
  }
}

// ---------------------------------------------------------------------------
// Global decayed attention, MFMA. Grid (slot 16, h 16, par 2).
// Block handles t-tiles {slot, 31-slot}; s-tiles of parity par.
// Staging via global_load_lds (async). Writes partial O (bf16) to y0/y1.
// qkv rows: [q(1024) | k(256) | v(256)], vtb = v^T [256][2048].
// ---------------------------------------------------------------------------
__global__ __launch_bounds__(256) void global_attn_mfma(
    const short* __restrict__ qkv, const short* __restrict__ vtb,
    const float* __restrict__ lac, const float* __restrict__ insc,
    short* __restrict__ y0, short* __restrict__ y1) {
  const int slot = blockIdx.x, h = blockIdx.y, par = blockIdx.z;
  const int kh = h >> 2;
  __shared__ short Qs[64 * 64], Ks[64 * 64], Vts[64 * 64], Ps[64 * 64];
  __shared__ float lacq[64], lacs[64], inss[64];
  const int tid = threadIdx.x, lane = tid & 63, wid = tid >> 6;
  const int l15 = lane & 15, lq = lane >> 4;
  const int srow = lane >> 3;
  const int sc16 = (lane & 7) ^ srow;
  short* yout = par ? y1 : y0;
  for (int rep = 0; rep < 2; ++rep) {
    const int tt = rep ? 31 - slot : slot;
    __syncthreads();
#pragma unroll
    for (int i = 0; i < 2; ++i) {
      int jj = wid * 2 + i;
      int row = jj * 8 + srow;
      gload16(qkv + (size_t)(tt * 64 + row) * 1536 + h * 64 + sc16 * 8,
              &Qs[jj * 512]);
    }
    if (tid < 64) lacq[tid] = lac[h * 2048 + tt * 64 + tid];
    f32x4 o[4];
#pragma unroll
    for (int nt = 0; nt < 4; ++nt) o[nt] = {0.f, 0.f, 0.f, 0.f};
    for (int st = par; st <= tt; st += 2) {
      __syncthreads();
#pragma unroll
      for (int i = 0; i < 2; ++i) {
        int jj = wid * 2 + i;
        int row = jj * 8 + srow;
        gload16(qkv + (size_t)(st * 64 + row) * 1536 + 1024 + kh * 64 + sc16 * 8,
                &Ks[jj * 512]);
        gload16(vtb + (size_t)(kh * 64 + row) * 2048 + st * 64 + sc16 * 8,
                &Vts[jj * 512]);
      }
      if (tid < 64) {
        lacs[tid] = lac[h * 2048 + st * 64 + tid];
        inss[tid] = insc[h * 2048 + st * 64 + tid];
      }
      __syncthreads();
      // S = Q @ K^T  (wave strip: rows wid*16..+15)
      const int qr = wid * 16 + l15;
      bf16x8 aq[2];
#pragma unroll
      for (int ks = 0; ks < 2; ++ks) {
        int c16 = ks * 4 + lq;
        aq[ks] = *(const bf16x8*)&Qs[(qr * 8 + (c16 ^ (qr & 7))) * 8];
      }
      f32x4 sv[4];
#pragma unroll
      for (int nt = 0; nt < 4; ++nt) {
        int kr = nt * 16 + l15;
        bf16x8 bk0 = *(const bf16x8*)&Ks[(kr * 8 + ((0 + lq) ^ (kr & 7))) * 8];
        bf16x8 bk1 = *(const bf16x8*)&Ks[(kr * 8 + ((4 + lq) ^ (kr & 7))) * 8];
        f32x4 z = {0.f, 0.f, 0.f, 0.f};
        z = MFMA16(aq[0], bk0, z);
        z = MFMA16(aq[1], bk1, z);
        sv[nt] = z;
      }
      // decay/mask -> P (bf16, swizzled)
      const bool diag = (st == tt);
#pragma unroll
      for (int nt = 0; nt < 4; ++nt) {
        int col = nt * 16 + l15;
        float ls = lacs[col], is = inss[col];
#pragma unroll
        for (int r = 0; r < 4; ++r) {
          int row = wid * 16 + lq * 4 + r;
          float d = lacq[row] - ls;
          float w = __expf(fminf(d, 0.f)) * is;
          if (diag && col > row) w = 0.f;
          Ps[(row * 8 + ((col >> 3) ^ (row & 7))) * 8 + (col & 7)] = f2b(sv[nt][r] * w);
        }
      }
      __syncthreads();
      // O += P @ V   (Vt layout [d][s])
      bf16x8 ap[2];
#pragma unroll
      for (int ks = 0; ks < 2; ++ks) {
        int c16 = ks * 4 + lq;
        ap[ks] = *(const bf16x8*)&Ps[(qr * 8 + (c16 ^ (qr & 7))) * 8];
      }
#pragma unroll
      for (int nt = 0; nt < 4; ++nt) {
        int vr = nt * 16 + l15;
        bf16x8 bv0 = *(const bf16x8*)&Vts[(vr * 8 + ((0 + lq) ^ (vr & 7))) * 8];
        bf16x8 bv1 = *(const bf16x8*)&Vts[(vr * 8 + ((4 + lq) ^ (vr & 7))) * 8];
        o[nt] = MFMA16(ap[0], bv0, o[nt]);
        o[nt] = MFMA16(ap[1], bv1, o[nt]);
      }
    }
#pragma unroll
    for (int nt = 0; nt < 4; ++nt)
#pragma unroll
      for (int r = 0; r < 4; ++r) {
        int row_g = tt * 64 + wid * 16 + lq * 4 + r;
        int colg = h * 64 + nt * 16 + l15;
        yout[(size_t)row_g * 1024 + colg] = f2b(o[nt][r]);
      }
  }
}

// ---------------------------------------------------------------------------
// Local windowed softmax attention, MFMA. Grid (32 q-strips, 16 h).
// ---------------------------------------------------------------------------
__global__ __launch_bounds__(256) void local_attn_mfma(
    const short* __restrict__ qkv, const short* __restrict__ vtb,
    short* __restrict__ yl) {
  const int half = blockIdx.x & 1, wb = blockIdx.x >> 1, h = blockIdx.y;
  const int kh = h >> 2, t0 = wb * 128;
  __shared__ short Qs[64 * 64];
  __shared__ short Ks[128 * 64];
  __shared__ short Vts[64 * 128];  // [d][s], 16 chunks/row
  __shared__ short Ps[64 * 128];
  const int tid = threadIdx.x, lane = tid & 63, wid = tid >> 6;
  const int l15 = lane & 15, lq = lane >> 4;
#pragma unroll
  for (int i = 0; i < 2; ++i) {
    int c = tid + 256 * i;
    int row = c >> 3, cc = c & 7;
    *(float4*)&Qs[(row * 8 + (cc ^ (row & 7))) * 8] =
        *(const float4*)&qkv[(size_t)(t0 + half * 64 + row) * 1536 + h * 64 + cc * 8];
  }
#pragma unroll
  for (int i = 0; i < 4; ++i) {
    int c = tid + 256 * i;
    int row = c >> 3, cc = c & 7;
    *(float4*)&Ks[(row * 8 + (cc ^ (row & 7))) * 8] =
        *(const float4*)&qkv[(size_t)(t0 + row) * 1536 + 1024 + kh * 64 + cc * 8];
  }
#pragma unroll
  for (int i = 0; i < 4; ++i) {
    int c = tid + 256 * i;
    int row = c >> 4, cc = c & 15;
    int sw = (row * 16 + ((cc & 8) | ((cc & 7) ^ (row & 7)))) * 8;
    *(float4*)&Vts[sw] = *(const float4*)&vtb[(size_t)(kh * 64 + row) * 2048 + t0 + cc * 8];
  }
  __syncthreads();
  const int qr = wid * 16 + l15;
  bf16x8 aq[2];
#pragma unroll
  for (int ks = 0; ks < 2; ++ks) {
    int c16 = ks * 4 + lq;
    aq[ks] = *(const bf16x8*)&Qs[(qr * 8 + (c16 ^ (qr & 7))) * 8];
  }
  f32x4 sv[2][4];
  const int nst = half + 1;
  for (int st = 0; st < nst; ++st)
#pragma unroll
    for (int nt = 0; nt < 4; ++nt) {
      int kr = st * 64 + nt * 16 + l15;
      bf16x8 bk0 = *(const bf16x8*)&Ks[(kr * 8 + ((0 + lq) ^ (kr & 7))) * 8];
      bf16x8 bk1 = *(const bf16x8*)&Ks[(kr * 8 + ((4 + lq) ^ (kr & 7))) * 8];
      f32x4 z = {0.f, 0.f, 0.f, 0.f};
      z = MFMA16(aq[0], bk0, z);
      z = MFMA16(aq[1], bk1, z);
      sv[st][nt] = z;
    }
  float mrow[4], ssum[4];
#pragma unroll
  for (int r = 0; r < 4; ++r) mrow[r] = -1e30f;
  for (int st = 0; st < nst; ++st)
#pragma unroll
    for (int nt = 0; nt < 4; ++nt) {
      int col = st * 64 + nt * 16 + l15;
#pragma unroll
      for (int r = 0; r < 4; ++r) {
        int row = half * 64 + wid * 16 + lq * 4 + r;
        float v = (col <= row) ? sv[st][nt][r] * 0.125f : -1e30f;
        sv[st][nt][r] = v;
        mrow[r] = fmaxf(mrow[r], v);
      }
    }
#pragma unroll
  for (int r = 0; r < 4; ++r) {
    for (int off = 1; off < 16; off <<= 1)
      mrow[r] = fmaxf(mrow[r], __shfl_xor(mrow[r], off, 64));
    ssum[r] = 0.f;
  }
  for (int st = 0; st < nst; ++st)
#pragma unroll
    for (int nt = 0; nt < 4; ++nt) {
      int col = st * 64 + nt * 16 + l15;
#pragma unroll
      for (int r = 0; r < 4; ++r) {
        float e = __expf(sv[st][nt][r] - mrow[r]);
        ssum[r] += e;
        int row = wid * 16 + lq * 4 + r;
        int c16 = col >> 3;
        Ps[(row * 16 + ((c16 & 8) | ((c16 & 7) ^ (row & 7)))) * 8 + (col & 7)] = f2b(e);
      }
    }
#pragma unroll
  for (int r = 0; r < 4; ++r) {
    for (int off = 1; off < 16; off <<= 1) ssum[r] += __shfl_xor(ssum[r], off, 64);
    ssum[r] = 1.f / ssum[r];
  }
  __syncthreads();
  f32x4 o[4];
#pragma unroll
  for (int nt = 0; nt < 4; ++nt) o[nt] = {0.f, 0.f, 0.f, 0.f};
  for (int ks = 0; ks < nst * 2; ++ks) {
    int c16 = ks * 4 + lq;
    bf16x8 ap = *(const bf16x8*)&Ps[(qr * 16 + ((c16 & 8) | ((c16 & 7) ^ (qr & 7)))) * 8];
#pragma unroll
    for (int nt = 0; nt < 4; ++nt) {
      int vr = nt * 16 + l15;
      bf16x8 bv = *(const bf16x8*)&Vts[(vr * 16 + ((c16 & 8) | ((c16 & 7) ^ (vr & 7)))) * 8];
      o[nt] = MFMA16(ap, bv, o[nt]);
    }
  }
#pragma unroll
  for (int nt = 0; nt < 4; ++nt)
#pragma unroll
    for (int r = 0; r < 4; ++r) {
      int row_g = t0 + half * 64 + wid * 16 + lq * 4 + r;
      int colg = h * 64 + nt * 16 + l15;
      yl[(size_t)row_g * 1024 + colg] = f2b(o[nt][r] * ssum[r]);
    }
}

// ---------------------------------------------------------------------------
// RMSNorm over y = y0 + y1 + ylocal (bf16 partials); writes yn bf16.
// ---------------------------------------------------------------------------
__global__ __launch_bounds__(256) void rmsnorm_fuse(
    const short* __restrict__ y0, const short* __restrict__ y1,
    const short* __restrict__ ylc, const float* __restrict__ w,
    short* __restrict__ yn) {
  const int t = blockIdx.x, tid = threadIdx.x;
  __shared__ float red[4];
  __shared__ float rowv[1024];
  __shared__ float scale_sh;
  float ssum = 0.f;
  for (int c = tid; c < 1024; c += 256) {
    size_t idx = (size_t)t * 1024 + c;
    float v = b2f(y0[idx]) + b2f(y1[idx]) + b2f(ylc[idx]);
    rowv[c] = v;
    ssum = fmaf(v, v, ssum);
  }
  for (int off = 32; off > 0; off >>= 1) ssum += __shfl_down(ssum, off, 64);
  const int lane = tid & 63, wd = tid >> 6;
  if (lane == 0) red[wd] = ssum;
  __syncthreads();
  if (tid == 0)
    scale_sh = rsqrtf((red[0] + red[1] + red[2] + red[3]) * (1.0f / 1024.0f) + 1e-5f);
  __syncthreads();
  const float scale = scale_sh;
  for (int c = tid; c < 1024; c += 256)
    yn[(size_t)t * 1024 + c] = f2b(rowv[c] * scale * w[c]);
}

// ---------------------------------------------------------------------------
extern "C" void kernel_launch(void* const* d_in, const int* in_sizes, int n_in,
                              void* d_out, int out_size, void* d_ws,
                              size_t ws_size, hipStream_t stream) {
  const float* x = (const float*)d_in[0];
  const float* Wq = (const float*)d_in[1];
  const float* Wk = (const float*)d_in[2];
  const float* Wv = (const float*)d_in[3];
  const float* Wc = (const float*)d_in[4];
  const float* Wg = (const float*)d_in[5];
  const float* bg = (const float*)d_in[6];
  const float* rmsw = (const float*)d_in[7];
  float* out = (float*)d_out;

  short* wqkvT = (short*)d_ws;               // [1536][1024]
  short* wcT = wqkvT + 1536 * 1024;          // [1024][1024]
  short* qkvb = wcT + 1024 * 1024;           // [2048][1536]
  short* vtb = qkvb + 2048 * 1536;           // [256][2048]
  float* gw = (float*)(vtb + 256 * 2048);    // [2048][16]
  float* lacw = gw + 2048 * 16;              // [16][2048]
  float* inscw = lacw + 16 * 2048;           // [16][2048]
  short* xb = (short*)(inscw + 16 * 2048);   // [2048][1024]
  short* y0 = xb;                            // alias: xb dead after qkv GEMM
  short* y1 = xb + 2048 * 1024;
  short* ylc = y1 + 2048 * 1024;
  short* yn = ylc + 2048 * 1024;

  cvt_f32_bf16<<<1024, 256, 0, stream>>>(x, xb, 2048 * 1024);
  transpose_cvt<<<dim3(32, 32), 256, 0, stream>>>(Wq, wqkvT, 1024, 1024);
  transpose_cvt<<<dim3(8, 32), 256, 0, stream>>>(Wk, wqkvT + 1024 * 1024, 1024, 256);
  transpose_cvt<<<dim3(8, 32), 256, 0, stream>>>(Wv, wqkvT + 1280 * 1024, 1024, 256);
  transpose_cvt<<<dim3(32, 32), 256, 0, stream>>>(Wc, wcT, 1024, 1024);
  gate_kernel<<<128, 256, 0, stream>>>(x, Wg, bg, gw);
  gate_scan_kernel<<<16, 256, 0, stream>>>(gw, lacw, inscw);
  gemm_mfma<true, true><<<768, 256, 0, stream>>>(xb, wqkvT, qkvb, 2048, 1536, 1024, 24);
  transpose_b16<<<dim3(8, 64), 256, 0, stream>>>(qkvb + 1280, 1536, vtb, 2048, 256);
  global_attn_mfma<<<dim3(16, 16, 2), 256, 0, stream>>>(qkvb, vtb, lacw, inscw, y0, y1);
  local_attn_mfma<<<dim3(32, 16), 256, 0, stream>>>(qkvb, vtb, ylc);
  rmsnorm_fuse<<<2048, 256, 0, stream>>>(y0, y1, ylc, rmsw, yn);
  gemm_mfma<false, false><<<512, 256, 0, stream>>>(yn, wcT, out, 2048, 1024, 1024, 16);
}

// Round 6
// 168.767 us; speedup vs baseline: 3.7697x; 1.1116x over previous
//
#include <hip/hip_runtime.h>
#include <hip/hip_bf16.h>

// Dtype contract (established rounds 0-3): ALL inputs fp32, OUTPUT fp32
// (harness compares in bf16 domain, threshold ~2% of max => bf16 MFMA safe).
// Dims: B=1, T=2048, C=1024, H=16, HKV=4, DH=64, WIN=128.
// Round 6: dispatch-count reduction 13 -> 6 (prep fused; scan folded into QKV
// GEMM launch; V written transposed by the GEMM epilogue so the vtb transpose
// kernel disappears). Round-5 accounting: ~95 us of kernel work vs 187 us
// measured => ~7 us/dispatch serialization gap dominated.

typedef __attribute__((ext_vector_type(8))) short bf16x8;  // 8 bf16 = 4 VGPR
typedef __attribute__((ext_vector_type(4))) float f32x4;

#define MFMA16(a, b, c) __builtin_amdgcn_mfma_f32_16x16x32_bf16(a, b, c, 0, 0, 0)
#define LN10000_OVER_32 0.28782313662425575f

__device__ __forceinline__ short f2b(float f) {
  __hip_bfloat16 h = __float2bfloat16(f);
  return *reinterpret_cast<short*>(&h);
}
__device__ __forceinline__ float b2f(short s) {
  return __uint_as_float(((unsigned)(unsigned short)s) << 16);
}
// Async 16B/lane global->LDS copy. LDS dest = wave-uniform base + lane*16.
__device__ __forceinline__ void gload16(const void* g, void* l) {
  __builtin_amdgcn_global_load_lds(
      (const __attribute__((address_space(1))) void*)g,
      (__attribute__((address_space(3))) void*)l, 16, 0, 0);
}

// ---------------------------------------------------------------------------
// prep_fused: one launch for all input-only preprocessing.
//   blocks [0,1024)    : x fp32 -> bf16 (8 elts/thread)
//   blocks [1024,2048) : Wq  [1024][1024] -> wqkvT[0]       (transpose+cvt)
//   blocks [2048,2304) : Wk  [1024][256]  -> wqkvT+1024*1024
//   blocks [2304,2560) : Wv  [1024][256]  -> wqkvT+1280*1024
//   blocks [2560,3584) : Wc  [1024][1024] -> wcT
//   blocks [3584,3712) : gate logits g[t,h] = x@Wg + bg
// ---------------------------------------------------------------------------
__device__ __forceinline__ void transpose_cvt_body(
    const float* __restrict__ src, short* __restrict__ dst, int R, int C,
    int bx, int by, float* ts /* [32*33] */) {
  int c0 = bx * 32, r0 = by * 32;
  int tr = threadIdx.x >> 3, tc = (threadIdx.x & 7) * 4;
  float4 v = *(const float4*)&src[(size_t)(r0 + tr) * C + c0 + tc];
  ts[tr * 33 + tc] = v.x;
  ts[tr * 33 + tc + 1] = v.y;
  ts[tr * 33 + tc + 2] = v.z;
  ts[tr * 33 + tc + 3] = v.w;
  __syncthreads();
  alignas(8) short o[4];
#pragma unroll
  for (int i = 0; i < 4; ++i) o[i] = f2b(ts[(tc + i) * 33 + tr]);
  *(uint2*)&dst[(size_t)(c0 + tr) * R + r0 + tc] = *(uint2*)o;
}

__global__ __launch_bounds__(256) void prep_fused(
    const float* __restrict__ x, const float* __restrict__ Wq,
    const float* __restrict__ Wk, const float* __restrict__ Wv,
    const float* __restrict__ Wc, const float* __restrict__ Wg,
    const float* __restrict__ bg, short* __restrict__ xb,
    short* __restrict__ wqkvT, short* __restrict__ wcT,
    float* __restrict__ g) {
  __shared__ float ts[32 * 33];
  const int j = blockIdx.x;
  if (j < 1024) {
    int i = (j * 256 + threadIdx.x) * 8;
    float4 a = *(const float4*)(x + i);
    float4 b = *(const float4*)(x + i + 4);
    alignas(16) short o[8] = {f2b(a.x), f2b(a.y), f2b(a.z), f2b(a.w),
                              f2b(b.x), f2b(b.y), f2b(b.z), f2b(b.w)};
    *(float4*)(xb + i) = *(float4*)o;
  } else if (j < 2048) {
    int jj = j - 1024;
    transpose_cvt_body(Wq, wqkvT, 1024, 1024, jj & 31, jj >> 5, ts);
  } else if (j < 2304) {
    int jj = j - 2048;
    transpose_cvt_body(Wk, wqkvT + 1024 * 1024, 1024, 256, jj & 7, jj >> 3, ts);
  } else if (j < 2560) {
    int jj = j - 2304;
    transpose_cvt_body(Wv, wqkvT + 1280 * 1024, 1024, 256, jj & 7, jj >> 3, ts);
  } else if (j < 3584) {
    int jj = j - 2560;
    transpose_cvt_body(Wc, wcT, 1024, 1024, jj & 31, jj >> 5, ts);
  } else {
    int idx = (j - 3584) * 256 + threadIdx.x;  // t*16 + h
    int t = idx >> 4, h = idx & 15;
    const float* xr = x + (size_t)t * 1024;
    float acc = 0.f;
    for (int c = 0; c < 1024; c += 4) {
      float4 xv = *(const float4*)(xr + c);
      acc = fmaf(xv.x, Wg[(c + 0) * 16 + h], acc);
      acc = fmaf(xv.y, Wg[(c + 1) * 16 + h], acc);
      acc = fmaf(xv.z, Wg[(c + 2) * 16 + h], acc);
      acc = fmaf(xv.w, Wg[(c + 3) * 16 + h], acc);
    }
    g[idx] = acc + bg[h];
  }
}

// ---------------------------------------------------------------------------
// QKV GEMM + gate scan, one launch.
//   blocks [0,768)  : qkv = xb @ wqkvT^T   (64x64 tile, BK=64, async staging)
//     N-tiles bx<20 (q,k): rope epilogue -> qkvb (stride 1536)
//     N-tiles bx>=20 (v) : transposed epilogue -> vtb [256][2048] (short4)
//   blocks [768,784): per-head scan lac = cumsum log_sigmoid(g), insc.
// XCD swizzle: blocks sharing an A row-strip share id%8.
// ---------------------------------------------------------------------------
__global__ __launch_bounds__(256) void qkv_gemm_fused(
    const short* __restrict__ A, const short* __restrict__ Bt,
    short* __restrict__ qkvb, short* __restrict__ vtb,
    const float* __restrict__ g, float* __restrict__ lac,
    float* __restrict__ insc) {
  __shared__ short As[64 * 64];
  __shared__ short Bs[64 * 64];
  __shared__ float part[256];
  const int id = blockIdx.x;
  const int tid = threadIdx.x;
  if (id >= 768) {
    // ---- gate scan (verified round-4 body, head-major outputs) ----
    const int h = id - 768;
    float vals[8];
    float local = 0.f;
#pragma unroll
    for (int i = 0; i < 8; ++i) {
      int t = tid * 8 + i;
      float gv = g[t * 16 + h];
      float la = (gv > 0.f) ? -log1pf(expf(-gv)) : (gv - log1pf(expf(gv)));
      insc[h * 2048 + t] = 1.f / (1.f + expf(gv));
      vals[i] = la;
      local += la;
    }
    part[tid] = local;
    __syncthreads();
    for (int off = 1; off < 256; off <<= 1) {
      float add = (tid >= off) ? part[tid - off] : 0.f;
      __syncthreads();
      part[tid] += add;
      __syncthreads();
    }
    float run = (tid > 0) ? part[tid - 1] : 0.f;
#pragma unroll
    for (int i = 0; i < 8; ++i) {
      run += vals[i];
      lac[h * 2048 + tid * 8 + i] = run;
    }
    return;
  }
  const int lane = tid & 63, wid = tid >> 6;
  const int l15 = lane & 15, lq = lane >> 4;
  const int jlin = id >> 3;
  const int by = (id & 7) + 8 * (jlin / 24);
  const int bx = jlin % 24;
  const int m0 = by * 64, n0 = bx * 64;
  const int K = 1024;
  const int srow = lane >> 3;
  const int sc16 = (lane & 7) ^ srow;
  f32x4 acc[4];
#pragma unroll
  for (int nt = 0; nt < 4; ++nt) acc[nt] = {0.f, 0.f, 0.f, 0.f};
  for (int kt = 0; kt < K; kt += 64) {
    __syncthreads();
#pragma unroll
    for (int i = 0; i < 2; ++i) {
      int jj = wid * 2 + i;
      int row = jj * 8 + srow;
      gload16(A + (size_t)(m0 + row) * K + kt + sc16 * 8, &As[jj * 512]);
      gload16(Bt + (size_t)(n0 + row) * K + kt + sc16 * 8, &Bs[jj * 512]);
    }
    __syncthreads();
    bf16x8 af[2], bfr[4][2];
#pragma unroll
    for (int ks = 0; ks < 2; ++ks) {
      int c16 = ks * 4 + lq;
      int ar = wid * 16 + l15;
      af[ks] = *(const bf16x8*)&As[(ar * 8 + (c16 ^ (ar & 7))) * 8];
#pragma unroll
      for (int nt = 0; nt < 4; ++nt) {
        int br = nt * 16 + l15;
        bfr[nt][ks] = *(const bf16x8*)&Bs[(br * 8 + (c16 ^ (br & 7))) * 8];
      }
    }
#pragma unroll
    for (int ks = 0; ks < 2; ++ks)
#pragma unroll
      for (int nt = 0; nt < 4; ++nt)
        acc[nt] = MFMA16(af[ks], bfr[nt][ks], acc[nt]);
  }
  if (bx >= 20) {
    // V tile: write transposed, vtb[d][t], packed short4 over r (contig rows)
    const int row0 = m0 + wid * 16 + lq * 4;
#pragma unroll
    for (int nt = 0; nt < 4; ++nt) {
      int vcol = (n0 - 1280) + nt * 16 + l15;
      alignas(8) short o4[4];
#pragma unroll
      for (int r = 0; r < 4; ++r) o4[r] = f2b(acc[nt][r]);
      *(uint2*)&vtb[(size_t)vcol * 2048 + row0] = *(uint2*)o4;
    }
    return;
  }
#pragma unroll
  for (int r = 0; r < 4; ++r) {
    int row_g = m0 + wid * 16 + lq * 4 + r;  // C/D: row=(lane>>4)*4+reg
    float t = (float)row_g;
#pragma unroll
    for (int nt = 0; nt < 2; ++nt) {
      int d = nt * 16 + l15;  // 0..31
      float th = t * __expf(-LN10000_OVER_32 * (float)d);
      float cs = cosf(th), sn = sinf(th);
      float a = acc[nt][r], b = acc[nt + 2][r];
      qkvb[(size_t)row_g * 1536 + n0 + d] = f2b(a * cs - b * sn);
      qkvb[(size_t)row_g * 1536 + n0 + d + 32] = f2b(b * cs + a * sn);
    }
  }
}

// ---------------------------------------------------------------------------
// Out projection GEMM: out[M,N] = A @ Bt^T, fp32 out. 64x64 tile, async stage.
// ---------------------------------------------------------------------------
__global__ __launch_bounds__(256) void out_gemm(
    const short* __restrict__ A, const short* __restrict__ Bt,
    float* __restrict__ C, int M, int N, int K, int nbx) {
  __shared__ short As[64 * 64];
  __shared__ short Bs[64 * 64];
  const int tid = threadIdx.x, lane = tid & 63, wid = tid >> 6;
  const int l15 = lane & 15, lq = lane >> 4;
  const int id = blockIdx.x;
  const int jlin = id >> 3;
  const int by = (id & 7) + 8 * (jlin / nbx);
  const int bx = jlin % nbx;
  const int m0 = by * 64, n0 = bx * 64;
  const int srow = lane >> 3;
  const int sc16 = (lane & 7) ^ srow;
  f32x4 acc[4];
#pragma unroll
  for (int nt = 0; nt < 4; ++nt) acc[nt] = {0.f, 0.f, 0.f, 0.f};
  for (int kt = 0; kt < K; kt += 64) {
    __syncthreads();
#pragma unroll
    for (int i = 0; i < 2; ++i) {
      int jj = wid * 2 + i;
      int row = jj * 8 + srow;
      gload16(A + (size_t)(m0 + row) * K + kt + sc16 * 8, &As[jj * 512]);
      gload16(Bt + (size_t)(n0 + row) * K + kt + sc16 * 8, &Bs[jj * 512]);
    }
    __syncthreads();
    bf16x8 af[2], bfr[4][2];
#pragma unroll
    for (int ks = 0; ks < 2; ++ks) {
      int c16 = ks * 4 + lq;
      int ar = wid * 16 + l15;
      af[ks] = *(const bf16x8*)&As[(ar * 8 + (c16 ^ (ar & 7))) * 8];
#pragma unroll
      for (int nt = 0; nt < 4; ++nt) {
        int br = nt * 16 + l15;
        bfr[nt][ks] = *(const bf16x8*)&Bs[(br * 8 + (c16 ^ (br & 7))) * 8];
      }
    }
#pragma unroll
    for (int ks = 0; ks < 2; ++ks)
#pragma unroll
      for (int nt = 0; nt < 4; ++nt)
        acc[nt] = MFMA16(af[ks], bfr[nt][ks], acc[nt]);
  }
#pragma unroll
  for (int r = 0; r < 4; ++r) {
    int row_g = m0 + wid * 16 + lq * 4 + r;
#pragma unroll
    for (int nt = 0; nt < 4; ++nt)
      C[(size_t)row_g * N + n0 + nt * 16 + l15] = acc[nt][r];
  }
}

// ---------------------------------------------------------------------------
// Global decayed attention, MFMA. Grid (slot 16, h 16, par 2).
// ---------------------------------------------------------------------------
__global__ __launch_bounds__(256) void global_attn_mfma(
    const short* __restrict__ qkv, const short* __restrict__ vtb,
    const float* __restrict__ lac, const float* __restrict__ insc,
    short* __restrict__ y0, short* __restrict__ y1) {
  const int slot = blockIdx.x, h = blockIdx.y, par = blockIdx.z;
  const int kh = h >> 2;
  __shared__ short Qs[64 * 64], Ks[64 * 64], Vts[64 * 64], Ps[64 * 64];
  __shared__ float lacq[64], lacs[64], inss[64];
  const int tid = threadIdx.x, lane = tid & 63, wid = tid >> 6;
  const int l15 = lane & 15, lq = lane >> 4;
  const int srow = lane >> 3;
  const int sc16 = (lane & 7) ^ srow;
  short* yout = par ? y1 : y0;
  for (int rep = 0; rep < 2; ++rep) {
    const int tt = rep ? 31 - slot : slot;
    __syncthreads();
#pragma unroll
    for (int i = 0; i < 2; ++i) {
      int jj = wid * 2 + i;
      int row = jj * 8 + srow;
      gload16(qkv + (size_t)(tt * 64 + row) * 1536 + h * 64 + sc16 * 8,
              &Qs[jj * 512]);
    }
    if (tid < 64) lacq[tid] = lac[h * 2048 + tt * 64 + tid];
    f32x4 o[4];
#pragma unroll
    for (int nt = 0; nt < 4; ++nt) o[nt] = {0.f, 0.f, 0.f, 0.f};
    for (int st = par; st <= tt; st += 2) {
      __syncthreads();
#pragma unroll
      for (int i = 0; i < 2; ++i) {
        int jj = wid * 2 + i;
        int row = jj * 8 + srow;
        gload16(qkv + (size_t)(st * 64 + row) * 1536 + 1024 + kh * 64 + sc16 * 8,
                &Ks[jj * 512]);
        gload16(vtb + (size_t)(kh * 64 + row) * 2048 + st * 64 + sc16 * 8,
                &Vts[jj * 512]);
      }
      if (tid < 64) {
        lacs[tid] = lac[h * 2048 + st * 64 + tid];
        inss[tid] = insc[h * 2048 + st * 64 + tid];
      }
      __syncthreads();
      const int qr = wid * 16 + l15;
      bf16x8 aq[2];
#pragma unroll
      for (int ks = 0; ks < 2; ++ks) {
        int c16 = ks * 4 + lq;
        aq[ks] = *(const bf16x8*)&Qs[(qr * 8 + (c16 ^ (qr & 7))) * 8];
      }
      f32x4 sv[4];
#pragma unroll
      for (int nt = 0; nt < 4; ++nt) {
        int kr = nt * 16 + l15;
        bf16x8 bk0 = *(const bf16x8*)&Ks[(kr * 8 + ((0 + lq) ^ (kr & 7))) * 8];
        bf16x8 bk1 = *(const bf16x8*)&Ks[(kr * 8 + ((4 + lq) ^ (kr & 7))) * 8];
        f32x4 z = {0.f, 0.f, 0.f, 0.f};
        z = MFMA16(aq[0], bk0, z);
        z = MFMA16(aq[1], bk1, z);
        sv[nt] = z;
      }
      const bool diag = (st == tt);
#pragma unroll
      for (int nt = 0; nt < 4; ++nt) {
        int col = nt * 16 + l15;
        float ls = lacs[col], is = inss[col];
#pragma unroll
        for (int r = 0; r < 4; ++r) {
          int row = wid * 16 + lq * 4 + r;
          float d = lacq[row] - ls;
          float w = __expf(fminf(d, 0.f)) * is;
          if (diag && col > row) w = 0.f;
          Ps[(row * 8 + ((col >> 3) ^ (row & 7))) * 8 + (col & 7)] = f2b(sv[nt][r] * w);
        }
      }
      __syncthreads();
      bf16x8 ap[2];
#pragma unroll
      for (int ks = 0; ks < 2; ++ks) {
        int c16 = ks * 4 + lq;
        ap[ks] = *(const bf16x8*)&Ps[(qr * 8 + (c16 ^ (qr & 7))) * 8];
      }
#pragma unroll
      for (int nt = 0; nt < 4; ++nt) {
        int vr = nt * 16 + l15;
        bf16x8 bv0 = *(const bf16x8*)&Vts[(vr * 8 + ((0 + lq) ^ (vr & 7))) * 8];
        bf16x8 bv1 = *(const bf16x8*)&Vts[(vr * 8 + ((4 + lq) ^ (vr & 7))) * 8];
        o[nt] = MFMA16(ap[0], bv0, o[nt]);
        o[nt] = MFMA16(ap[1], bv1, o[nt]);
      }
    }
#pragma unroll
    for (int nt = 0; nt < 4; ++nt)
#pragma unroll
      for (int r = 0; r < 4; ++r) {
        int row_g = tt * 64 + wid * 16 + lq * 4 + r;
        int colg = h * 64 + nt * 16 + l15;
        yout[(size_t)row_g * 1024 + colg] = f2b(o[nt][r]);
      }
  }
}

// ---------------------------------------------------------------------------
// Local windowed softmax attention, MFMA. Grid (32 q-strips, 16 h).
// ---------------------------------------------------------------------------
__global__ __launch_bounds__(256) void local_attn_mfma(
    const short* __restrict__ qkv, const short* __restrict__ vtb,
    short* __restrict__ yl) {
  const int half = blockIdx.x & 1, wb = blockIdx.x >> 1, h = blockIdx.y;
  const int kh = h >> 2, t0 = wb * 128;
  __shared__ short Qs[64 * 64];
  __shared__ short Ks[128 * 64];
  __shared__ short Vts[64 * 128];
  __shared__ short Ps[64 * 128];
  const int tid = threadIdx.x, lane = tid & 63, wid = tid >> 6;
  const int l15 = lane & 15, lq = lane >> 4;
#pragma unroll
  for (int i = 0; i < 2; ++i) {
    int c = tid + 256 * i;
    int row = c >> 3, cc = c & 7;
    *(float4*)&Qs[(row * 8 + (cc ^ (row & 7))) * 8] =
        *(const float4*)&qkv[(size_t)(t0 + half * 64 + row) * 1536 + h * 64 + cc * 8];
  }
#pragma unroll
  for (int i = 0; i < 4; ++i) {
    int c = tid + 256 * i;
    int row = c >> 3, cc = c & 7;
    *(float4*)&Ks[(row * 8 + (cc ^ (row & 7))) * 8] =
        *(const float4*)&qkv[(size_t)(t0 + row) * 1536 + 1024 + kh * 64 + cc * 8];
  }
#pragma unroll
  for (int i = 0; i < 4; ++i) {
    int c = tid + 256 * i;
    int row = c >> 4, cc = c & 15;
    int sw = (row * 16 + ((cc & 8) | ((cc & 7) ^ (row & 7)))) * 8;
    *(float4*)&Vts[sw] = *(const float4*)&vtb[(size_t)(kh * 64 + row) * 2048 + t0 + cc * 8];
  }
  __syncthreads();
  const int qr = wid * 16 + l15;
  bf16x8 aq[2];
#pragma unroll
  for (int ks = 0; ks < 2; ++ks) {
    int c16 = ks * 4 + lq;
    aq[ks] = *(const bf16x8*)&Qs[(qr * 8 + (c16 ^ (qr & 7))) * 8];
  }
  f32x4 sv[2][4];
  const int nst = half + 1;
  for (int st = 0; st < nst; ++st)
#pragma unroll
    for (int nt = 0; nt < 4; ++nt) {
      int kr = st * 64 + nt * 16 + l15;
      bf16x8 bk0 = *(const bf16x8*)&Ks[(kr * 8 + ((0 + lq) ^ (kr & 7))) * 8];
      bf16x8 bk1 = *(const bf16x8*)&Ks[(kr * 8 + ((4 + lq) ^ (kr & 7))) * 8];
      f32x4 z = {0.f, 0.f, 0.f, 0.f};
      z = MFMA16(aq[0], bk0, z);
      z = MFMA16(aq[1], bk1, z);
      sv[st][nt] = z;
    }
  float mrow[4], ssum[4];
#pragma unroll
  for (int r = 0; r < 4; ++r) mrow[r] = -1e30f;
  for (int st = 0; st < nst; ++st)
#pragma unroll
    for (int nt = 0; nt < 4; ++nt) {
      int col = st * 64 + nt * 16 + l15;
#pragma unroll
      for (int r = 0; r < 4; ++r) {
        int row = half * 64 + wid * 16 + lq * 4 + r;
        float v = (col <= row) ? sv[st][nt][r] * 0.125f : -1e30f;
        sv[st][nt][r] = v;
        mrow[r] = fmaxf(mrow[r], v);
      }
    }
#pragma unroll
  for (int r = 0; r < 4; ++r) {
    for (int off = 1; off < 16; off <<= 1)
      mrow[r] = fmaxf(mrow[r], __shfl_xor(mrow[r], off, 64));
    ssum[r] = 0.f;
  }
  for (int st = 0; st < nst; ++st)
#pragma unroll
    for (int nt = 0; nt < 4; ++nt) {
      int col = st * 64 + nt * 16 + l15;
#pragma unroll
      for (int r = 0; r < 4; ++r) {
        float e = __expf(sv[st][nt][r] - mrow[r]);
        ssum[r] += e;
        int row = wid * 16 + lq * 4 + r;
        int c16 = col >> 3;
        Ps[(row * 16 + ((c16 & 8) | ((c16 & 7) ^ (row & 7)))) * 8 + (col & 7)] = f2b(e);
      }
    }
#pragma unroll
  for (int r = 0; r < 4; ++r) {
    for (int off = 1; off < 16; off <<= 1) ssum[r] += __shfl_xor(ssum[r], off, 64);
    ssum[r] = 1.f / ssum[r];
  }
  __syncthreads();
  f32x4 o[4];
#pragma unroll
  for (int nt = 0; nt < 4; ++nt) o[nt] = {0.f, 0.f, 0.f, 0.f};
  for (int ks = 0; ks < nst * 2; ++ks) {
    int c16 = ks * 4 + lq;
    bf16x8 ap = *(const bf16x8*)&Ps[(qr * 16 + ((c16 & 8) | ((c16 & 7) ^ (qr & 7)))) * 8];
#pragma unroll
    for (int nt = 0; nt < 4; ++nt) {
      int vr = nt * 16 + l15;
      bf16x8 bv = *(const bf16x8*)&Vts[(vr * 16 + ((c16 & 8) | ((c16 & 7) ^ (vr & 7)))) * 8];
      o[nt] = MFMA16(ap, bv, o[nt]);
    }
  }
#pragma unroll
  for (int nt = 0; nt < 4; ++nt)
#pragma unroll
    for (int r = 0; r < 4; ++r) {
      int row_g = t0 + half * 64 + wid * 16 + lq * 4 + r;
      int colg = h * 64 + nt * 16 + l15;
      yl[(size_t)row_g * 1024 + colg] = f2b(o[nt][r] * ssum[r]);
    }
}

// ---------------------------------------------------------------------------
// RMSNorm over y = y0 + y1 + ylocal (bf16 partials); writes yn bf16.
// ---------------------------------------------------------------------------
__global__ __launch_bounds__(256) void rmsnorm_fuse(
    const short* __restrict__ y0, const short* __restrict__ y1,
    const short* __restrict__ ylc, const float* __restrict__ w,
    short* __restrict__ yn) {
  const int t = blockIdx.x, tid = threadIdx.x;
  __shared__ float red[4];
  __shared__ float rowv[1024];
  __shared__ float scale_sh;
  float ssum = 0.f;
  for (int c = tid; c < 1024; c += 256) {
    size_t idx = (size_t)t * 1024 + c;
    float v = b2f(y0[idx]) + b2f(y1[idx]) + b2f(ylc[idx]);
    rowv[c] = v;
    ssum = fmaf(v, v, ssum);
  }
  for (int off = 32; off > 0; off >>= 1) ssum += __shfl_down(ssum, off, 64);
  const int lane = tid & 63, wd = tid >> 6;
  if (lane == 0) red[wd] = ssum;
  __syncthreads();
  if (tid == 0)
    scale_sh = rsqrtf((red[0] + red[1] + red[2] + red[3]) * (1.0f / 1024.0f) + 1e-5f);
  __syncthreads();
  const float scale = scale_sh;
  for (int c = tid; c < 1024; c += 256)
    yn[(size_t)t * 1024 + c] = f2b(rowv[c] * scale * w[c]);
}

// ---------------------------------------------------------------------------
extern "C" void kernel_launch(void* const* d_in, const int* in_sizes, int n_in,
                              void* d_out, int out_size, void* d_ws,
                              size_t ws_size, hipStream_t stream) {
  const float* x = (const float*)d_in[0];
  const float* Wq = (const float*)d_in[1];
  const float* Wk = (const float*)d_in[2];
  const float* Wv = (const float*)d_in[3];
  const float* Wc = (const float*)d_in[4];
  const float* Wg = (const float*)d_in[5];
  const float* bg = (const float*)d_in[6];
  const float* rmsw = (const float*)d_in[7];
  float* out = (float*)d_out;

  short* wqkvT = (short*)d_ws;               // [1536][1024]
  short* wcT = wqkvT + 1536 * 1024;          // [1024][1024]
  short* qkvb = wcT + 1024 * 1024;           // [2048][1536] (v region unused)
  short* vtb = qkvb + 2048 * 1536;           // [256][2048]
  float* gw = (float*)(vtb + 256 * 2048);    // [2048][16]
  float* lacw = gw + 2048 * 16;              // [16][2048]
  float* inscw = lacw + 16 * 2048;           // [16][2048]
  short* xb = (short*)(inscw + 16 * 2048);   // [2048][1024]
  short* y0 = xb;                            // alias: xb dead after qkv GEMM
  short* y1 = xb + 2048 * 1024;
  short* ylc = y1 + 2048 * 1024;
  short* yn = ylc + 2048 * 1024;

  prep_fused<<<3712, 256, 0, stream>>>(x, Wq, Wk, Wv, Wc, Wg, bg, xb, wqkvT,
                                       wcT, gw);
  qkv_gemm_fused<<<784, 256, 0, stream>>>(xb, wqkvT, qkvb, vtb, gw, lacw,
                                          inscw);
  global_attn_mfma<<<dim3(16, 16, 2), 256, 0, stream>>>(qkvb, vtb, lacw, inscw,
                                                        y0, y1);
  local_attn_mfma<<<dim3(32, 16), 256, 0, stream>>>(qkvb, vtb, ylc);
  rmsnorm_fuse<<<2048, 256, 0, stream>>>(y0, y1, ylc, rmsw, yn);
  out_gemm<<<512, 256, 0, stream>>>(yn, wcT, out, 2048, 1024, 1024, 16);
}

// Round 7
// 150.275 us; speedup vs baseline: 4.2336x; 1.1231x over previous
//
#include <hip/hip_runtime.h>
#include <hip/hip_bf16.h>

// Dtype contract (established rounds 0-3): ALL inputs fp32, OUTPUT fp32
// (harness compares in bf16 domain, threshold ~2% of max => bf16 MFMA safe).
// Dims: B=1, T=2048, C=1024, H=16, HKV=4, DH=64, WIN=128.
// Round 7: (a) gate-logit role re-parallelized (was a 128-block, 6%-occupancy
// latency tail dominating prep_fused at ~50 us; now 2048 blocks, 16 lanes per
// (t,h) dot product); (b) global+local attention merged into one launch
// (independent inputs; LDS union 57 KB keeps the same 2 blocks/CU residency).

typedef __attribute__((ext_vector_type(8))) short bf16x8;  // 8 bf16 = 4 VGPR
typedef __attribute__((ext_vector_type(4))) float f32x4;

#define MFMA16(a, b, c) __builtin_amdgcn_mfma_f32_16x16x32_bf16(a, b, c, 0, 0, 0)
#define LN10000_OVER_32 0.28782313662425575f

__device__ __forceinline__ short f2b(float f) {
  __hip_bfloat16 h = __float2bfloat16(f);
  return *reinterpret_cast<short*>(&h);
}
__device__ __forceinline__ float b2f(short s) {
  return __uint_as_float(((unsigned)(unsigned short)s) << 16);
}
// Async 16B/lane global->LDS copy. LDS dest = wave-uniform base + lane*16.
__device__ __forceinline__ void gload16(const void* g, void* l) {
  __builtin_amdgcn_global_load_lds(
      (const __attribute__((address_space(1))) void*)g,
      (__attribute__((address_space(3))) void*)l, 16, 0, 0);
}

// ---------------------------------------------------------------------------
// prep_fused: one launch for all input-only preprocessing.
//   blocks [0,2048)    : gate logits g[t,h] = x[t]@Wg[:,h] + bg[h]
//                        (block = one t; 16 lanes per h, K-chunk 64 each)
//   blocks [2048,3072) : x fp32 -> bf16 (8 elts/thread)
//   blocks [3072,4096) : Wq [1024][1024] -> wqkvT[0]      (transpose+cvt)
//   blocks [4096,4352) : Wk [1024][256]  -> wqkvT+1024*1024
//   blocks [4352,4608) : Wv [1024][256]  -> wqkvT+1280*1024
//   blocks [4608,5632) : Wc [1024][1024] -> wcT
// ---------------------------------------------------------------------------
__device__ __forceinline__ void transpose_cvt_body(
    const float* __restrict__ src, short* __restrict__ dst, int R, int C,
    int bx, int by, float* ts /* [32*33] */) {
  int c0 = bx * 32, r0 = by * 32;
  int tr = threadIdx.x >> 3, tc = (threadIdx.x & 7) * 4;
  float4 v = *(const float4*)&src[(size_t)(r0 + tr) * C + c0 + tc];
  ts[tr * 33 + tc] = v.x;
  ts[tr * 33 + tc + 1] = v.y;
  ts[tr * 33 + tc + 2] = v.z;
  ts[tr * 33 + tc + 3] = v.w;
  __syncthreads();
  alignas(8) short o[4];
#pragma unroll
  for (int i = 0; i < 4; ++i) o[i] = f2b(ts[(tc + i) * 33 + tr]);
  *(uint2*)&dst[(size_t)(c0 + tr) * R + r0 + tc] = *(uint2*)o;
}

__global__ __launch_bounds__(256) void prep_fused(
    const float* __restrict__ x, const float* __restrict__ Wq,
    const float* __restrict__ Wk, const float* __restrict__ Wv,
    const float* __restrict__ Wc, const float* __restrict__ Wg,
    const float* __restrict__ bg, short* __restrict__ xb,
    short* __restrict__ wqkvT, short* __restrict__ wcT,
    float* __restrict__ g) {
  __shared__ float ts[32 * 33];
  const int j = blockIdx.x;
  const int tid = threadIdx.x;
  if (j < 2048) {
    // gate logits for t = j. lanes: h = tid&15, K-chunk = tid>>4 (64 elts).
    const int t = j;
    const int h = tid & 15, chunk = tid >> 4;
    const float* xr = x + (size_t)t * 1024 + chunk * 64;
    const float* wg = Wg + (size_t)chunk * 64 * 16 + h;
    float acc = 0.f;
#pragma unroll
    for (int c = 0; c < 64; c += 4) {
      float4 xv = *(const float4*)(xr + c);
      acc = fmaf(xv.x, wg[(c + 0) * 16], acc);
      acc = fmaf(xv.y, wg[(c + 1) * 16], acc);
      acc = fmaf(xv.z, wg[(c + 2) * 16], acc);
      acc = fmaf(xv.w, wg[(c + 3) * 16], acc);
    }
    ts[chunk * 16 + h] = acc;
    __syncthreads();
    if (tid < 16) {
      float s = bg[tid];
#pragma unroll
      for (int i = 0; i < 16; ++i) s += ts[i * 16 + tid];
      g[t * 16 + tid] = s;
    }
  } else if (j < 3072) {
    int i = ((j - 2048) * 256 + tid) * 8;
    float4 a = *(const float4*)(x + i);
    float4 b = *(const float4*)(x + i + 4);
    alignas(16) short o[8] = {f2b(a.x), f2b(a.y), f2b(a.z), f2b(a.w),
                              f2b(b.x), f2b(b.y), f2b(b.z), f2b(b.w)};
    *(float4*)(xb + i) = *(float4*)o;
  } else if (j < 4096) {
    int jj = j - 3072;
    transpose_cvt_body(Wq, wqkvT, 1024, 1024, jj & 31, jj >> 5, ts);
  } else if (j < 4352) {
    int jj = j - 4096;
    transpose_cvt_body(Wk, wqkvT + 1024 * 1024, 1024, 256, jj & 7, jj >> 3, ts);
  } else if (j < 4608) {
    int jj = j - 4352;
    transpose_cvt_body(Wv, wqkvT + 1280 * 1024, 1024, 256, jj & 7, jj >> 3, ts);
  } else {
    int jj = j - 4608;
    transpose_cvt_body(Wc, wcT, 1024, 1024, jj & 31, jj >> 5, ts);
  }
}

// ---------------------------------------------------------------------------
// QKV GEMM + gate scan, one launch.
//   blocks [0,768)  : qkv = xb @ wqkvT^T   (64x64 tile, BK=64, async staging)
//     N-tiles bx<20 (q,k): rope epilogue -> qkvb (stride 1536)
//     N-tiles bx>=20 (v) : transposed epilogue -> vtb [256][2048] (short4)
//   blocks [768,784): per-head scan lac = cumsum log_sigmoid(g), insc.
// XCD swizzle: blocks sharing an A row-strip share id%8.
// ---------------------------------------------------------------------------
__global__ __launch_bounds__(256) void qkv_gemm_fused(
    const short* __restrict__ A, const short* __restrict__ Bt,
    short* __restrict__ qkvb, short* __restrict__ vtb,
    const float* __restrict__ g, float* __restrict__ lac,
    float* __restrict__ insc) {
  __shared__ short As[64 * 64];
  __shared__ short Bs[64 * 64];
  __shared__ float part[256];
  const int id = blockIdx.x;
  const int tid = threadIdx.x;
  if (id >= 768) {
    // ---- gate scan (verified round-4 body, head-major outputs) ----
    const int h = id - 768;
    float vals[8];
    float local = 0.f;
#pragma unroll
    for (int i = 0; i < 8; ++i) {
      int t = tid * 8 + i;
      float gv = g[t * 16 + h];
      float la = (gv > 0.f) ? -log1pf(expf(-gv)) : (gv - log1pf(expf(gv)));
      insc[h * 2048 + t] = 1.f / (1.f + expf(gv));
      vals[i] = la;
      local += la;
    }
    part[tid] = local;
    __syncthreads();
    for (int off = 1; off < 256; off <<= 1) {
      float add = (tid >= off) ? part[tid - off] : 0.f;
      __syncthreads();
      part[tid] += add;
      __syncthreads();
    }
    float run = (tid > 0) ? part[tid - 1] : 0.f;
#pragma unroll
    for (int i = 0; i < 8; ++i) {
      run += vals[i];
      lac[h * 2048 + tid * 8 + i] = run;
    }
    return;
  }
  const int lane = tid & 63, wid = tid >> 6;
  const int l15 = lane & 15, lq = lane >> 4;
  const int jlin = id >> 3;
  const int by = (id & 7) + 8 * (jlin / 24);
  const int bx = jlin % 24;
  const int m0 = by * 64, n0 = bx * 64;
  const int K = 1024;
  const int srow = lane >> 3;
  const int sc16 = (lane & 7) ^ srow;
  f32x4 acc[4];
#pragma unroll
  for (int nt = 0; nt < 4; ++nt) acc[nt] = {0.f, 0.f, 0.f, 0.f};
  for (int kt = 0; kt < K; kt += 64) {
    __syncthreads();
#pragma unroll
    for (int i = 0; i < 2; ++i) {
      int jj = wid * 2 + i;
      int row = jj * 8 + srow;
      gload16(A + (size_t)(m0 + row) * K + kt + sc16 * 8, &As[jj * 512]);
      gload16(Bt + (size_t)(n0 + row) * K + kt + sc16 * 8, &Bs[jj * 512]);
    }
    __syncthreads();
    bf16x8 af[2], bfr[4][2];
#pragma unroll
    for (int ks = 0; ks < 2; ++ks) {
      int c16 = ks * 4 + lq;
      int ar = wid * 16 + l15;
      af[ks] = *(const bf16x8*)&As[(ar * 8 + (c16 ^ (ar & 7))) * 8];
#pragma unroll
      for (int nt = 0; nt < 4; ++nt) {
        int br = nt * 16 + l15;
        bfr[nt][ks] = *(const bf16x8*)&Bs[(br * 8 + (c16 ^ (br & 7))) * 8];
      }
    }
#pragma unroll
    for (int ks = 0; ks < 2; ++ks)
#pragma unroll
      for (int nt = 0; nt < 4; ++nt)
        acc[nt] = MFMA16(af[ks], bfr[nt][ks], acc[nt]);
  }
  if (bx >= 20) {
    // V tile: write transposed, vtb[d][t], packed short4 over r (contig rows)
    const int row0 = m0 + wid * 16 + lq * 4;
#pragma unroll
    for (int nt = 0; nt < 4; ++nt) {
      int vcol = (n0 - 1280) + nt * 16 + l15;
      alignas(8) short o4[4];
#pragma unroll
      for (int r = 0; r < 4; ++r) o4[r] = f2b(acc[nt][r]);
      *(uint2*)&vtb[(size_t)vcol * 2048 + row0] = *(uint2*)o4;
    }
    return;
  }
#pragma unroll
  for (int r = 0; r < 4; ++r) {
    int row_g = m0 + wid * 16 + lq * 4 + r;  // C/D: row=(lane>>4)*4+reg
    float t = (float)row_g;
#pragma unroll
    for (int nt = 0; nt < 2; ++nt) {
      int d = nt * 16 + l15;  // 0..31
      float th = t * __expf(-LN10000_OVER_32 * (float)d);
      float cs = cosf(th), sn = sinf(th);
      float a = acc[nt][r], b = acc[nt + 2][r];
      qkvb[(size_t)row_g * 1536 + n0 + d] = f2b(a * cs - b * sn);
      qkvb[(size_t)row_g * 1536 + n0 + d + 32] = f2b(b * cs + a * sn);
    }
  }
}

// ---------------------------------------------------------------------------
// Out projection GEMM: out[M,N] = A @ Bt^T, fp32 out. 64x64 tile, async stage.
// ---------------------------------------------------------------------------
__global__ __launch_bounds__(256) void out_gemm(
    const short* __restrict__ A, const short* __restrict__ Bt,
    float* __restrict__ C, int M, int N, int K, int nbx) {
  __shared__ short As[64 * 64];
  __shared__ short Bs[64 * 64];
  const int tid = threadIdx.x, lane = tid & 63, wid = tid >> 6;
  const int l15 = lane & 15, lq = lane >> 4;
  const int id = blockIdx.x;
  const int jlin = id >> 3;
  const int by = (id & 7) + 8 * (jlin / nbx);
  const int bx = jlin % nbx;
  const int m0 = by * 64, n0 = bx * 64;
  const int srow = lane >> 3;
  const int sc16 = (lane & 7) ^ srow;
  f32x4 acc[4];
#pragma unroll
  for (int nt = 0; nt < 4; ++nt) acc[nt] = {0.f, 0.f, 0.f, 0.f};
  for (int kt = 0; kt < K; kt += 64) {
    __syncthreads();
#pragma unroll
    for (int i = 0; i < 2; ++i) {
      int jj = wid * 2 + i;
      int row = jj * 8 + srow;
      gload16(A + (size_t)(m0 + row) * K + kt + sc16 * 8, &As[jj * 512]);
      gload16(Bt + (size_t)(n0 + row) * K + kt + sc16 * 8, &Bs[jj * 512]);
    }
    __syncthreads();
    bf16x8 af[2], bfr[4][2];
#pragma unroll
    for (int ks = 0; ks < 2; ++ks) {
      int c16 = ks * 4 + lq;
      int ar = wid * 16 + l15;
      af[ks] = *(const bf16x8*)&As[(ar * 8 + (c16 ^ (ar & 7))) * 8];
#pragma unroll
      for (int nt = 0; nt < 4; ++nt) {
        int br = nt * 16 + l15;
        bfr[nt][ks] = *(const bf16x8*)&Bs[(br * 8 + (c16 ^ (br & 7))) * 8];
      }
    }
#pragma unroll
    for (int ks = 0; ks < 2; ++ks)
#pragma unroll
      for (int nt = 0; nt < 4; ++nt)
        acc[nt] = MFMA16(af[ks], bfr[nt][ks], acc[nt]);
  }
#pragma unroll
  for (int r = 0; r < 4; ++r) {
    int row_g = m0 + wid * 16 + lq * 4 + r;
#pragma unroll
    for (int nt = 0; nt < 4; ++nt)
      C[(size_t)row_g * N + n0 + nt * 16 + l15] = acc[nt][r];
  }
}

// ---------------------------------------------------------------------------
// attn_fused: global decayed attention (z=0) + local windowed attention (z=1),
// one launch. Grid (32, 16, 2). Bodies identical to the verified round-6
// kernels; LDS arrays unioned (SA/SB/SC/SD), ~57 KB -> 2 blocks/CU.
// ---------------------------------------------------------------------------
__global__ __launch_bounds__(256) void attn_fused(
    const short* __restrict__ qkv, const short* __restrict__ vtb,
    const float* __restrict__ lac, const float* __restrict__ insc,
    short* __restrict__ y0, short* __restrict__ y1, short* __restrict__ yl) {
  __shared__ short SA[64 * 64];   // global: Qs   | local: Qs
  __shared__ short SB[128 * 64];  // global: Ks(64*64) | local: Ks
  __shared__ short SC[64 * 128];  // global: Vts(64*64) | local: Vts
  __shared__ short SD[64 * 128];  // global: Ps(64*64)  | local: Ps
  __shared__ float lacq[64], lacs[64], inss[64];
  const int tid = threadIdx.x, lane = tid & 63, wid = tid >> 6;
  const int l15 = lane & 15, lq = lane >> 4;
  const int h = blockIdx.y;
  const int kh = h >> 2;
  if (blockIdx.z == 0) {
    // ---------------- global decayed attention ----------------
    const int slot = blockIdx.x & 15, par = blockIdx.x >> 4;
    short* Qs = SA;
    short* Ks = SB;
    short* Vts = SC;
    short* Ps = SD;
    const int srow = lane >> 3;
    const int sc16 = (lane & 7) ^ srow;
    short* yout = par ? y1 : y0;
    for (int rep = 0; rep < 2; ++rep) {
      const int tt = rep ? 31 - slot : slot;
      __syncthreads();
#pragma unroll
      for (int i = 0; i < 2; ++i) {
        int jj = wid * 2 + i;
        int row = jj * 8 + srow;
        gload16(qkv + (size_t)(tt * 64 + row) * 1536 + h * 64 + sc16 * 8,
                &Qs[jj * 512]);
      }
      if (tid < 64) lacq[tid] = lac[h * 2048 + tt * 64 + tid];
      f32x4 o[4];
#pragma unroll
      for (int nt = 0; nt < 4; ++nt) o[nt] = {0.f, 0.f, 0.f, 0.f};
      for (int st = par; st <= tt; st += 2) {
        __syncthreads();
#pragma unroll
        for (int i = 0; i < 2; ++i) {
          int jj = wid * 2 + i;
          int row = jj * 8 + srow;
          gload16(qkv + (size_t)(st * 64 + row) * 1536 + 1024 + kh * 64 + sc16 * 8,
                  &Ks[jj * 512]);
          gload16(vtb + (size_t)(kh * 64 + row) * 2048 + st * 64 + sc16 * 8,
                  &Vts[jj * 512]);
        }
        if (tid < 64) {
          lacs[tid] = lac[h * 2048 + st * 64 + tid];
          inss[tid] = insc[h * 2048 + st * 64 + tid];
        }
        __syncthreads();
        const int qr = wid * 16 + l15;
        bf16x8 aq[2];
#pragma unroll
        for (int ks = 0; ks < 2; ++ks) {
          int c16 = ks * 4 + lq;
          aq[ks] = *(const bf16x8*)&Qs[(qr * 8 + (c16 ^ (qr & 7))) * 8];
        }
        f32x4 sv[4];
#pragma unroll
        for (int nt = 0; nt < 4; ++nt) {
          int kr = nt * 16 + l15;
          bf16x8 bk0 = *(const bf16x8*)&Ks[(kr * 8 + ((0 + lq) ^ (kr & 7))) * 8];
          bf16x8 bk1 = *(const bf16x8*)&Ks[(kr * 8 + ((4 + lq) ^ (kr & 7))) * 8];
          f32x4 z = {0.f, 0.f, 0.f, 0.f};
          z = MFMA16(aq[0], bk0, z);
          z = MFMA16(aq[1], bk1, z);
          sv[nt] = z;
        }
        const bool diag = (st == tt);
#pragma unroll
        for (int nt = 0; nt < 4; ++nt) {
          int col = nt * 16 + l15;
          float ls = lacs[col], is = inss[col];
#pragma unroll
          for (int r = 0; r < 4; ++r) {
            int row = wid * 16 + lq * 4 + r;
            float d = lacq[row] - ls;
            float w = __expf(fminf(d, 0.f)) * is;
            if (diag && col > row) w = 0.f;
            Ps[(row * 8 + ((col >> 3) ^ (row & 7))) * 8 + (col & 7)] =
                f2b(sv[nt][r] * w);
          }
        }
        __syncthreads();
        bf16x8 ap[2];
#pragma unroll
        for (int ks = 0; ks < 2; ++ks) {
          int c16 = ks * 4 + lq;
          ap[ks] = *(const bf16x8*)&Ps[(qr * 8 + (c16 ^ (qr & 7))) * 8];
        }
#pragma unroll
        for (int nt = 0; nt < 4; ++nt) {
          int vr = nt * 16 + l15;
          bf16x8 bv0 = *(const bf16x8*)&Vts[(vr * 8 + ((0 + lq) ^ (vr & 7))) * 8];
          bf16x8 bv1 = *(const bf16x8*)&Vts[(vr * 8 + ((4 + lq) ^ (vr & 7))) * 8];
          o[nt] = MFMA16(ap[0], bv0, o[nt]);
          o[nt] = MFMA16(ap[1], bv1, o[nt]);
        }
      }
#pragma unroll
      for (int nt = 0; nt < 4; ++nt)
#pragma unroll
        for (int r = 0; r < 4; ++r) {
          int row_g = tt * 64 + wid * 16 + lq * 4 + r;
          int colg = h * 64 + nt * 16 + l15;
          yout[(size_t)row_g * 1024 + colg] = f2b(o[nt][r]);
        }
    }
  } else {
    // ---------------- local windowed softmax attention ----------------
    const int half = blockIdx.x & 1, wb = blockIdx.x >> 1;
    const int t0 = wb * 128;
    short* Qs = SA;
    short* Ks = SB;
    short* Vts = SC;
    short* Ps = SD;
#pragma unroll
    for (int i = 0; i < 2; ++i) {
      int c = tid + 256 * i;
      int row = c >> 3, cc = c & 7;
      *(float4*)&Qs[(row * 8 + (cc ^ (row & 7))) * 8] =
          *(const float4*)&qkv[(size_t)(t0 + half * 64 + row) * 1536 + h * 64 + cc * 8];
    }
#pragma unroll
    for (int i = 0; i < 4; ++i) {
      int c = tid + 256 * i;
      int row = c >> 3, cc = c & 7;
      *(float4*)&Ks[(row * 8 + (cc ^ (row & 7))) * 8] =
          *(const float4*)&qkv[(size_t)(t0 + row) * 1536 + 1024 + kh * 64 + cc * 8];
    }
#pragma unroll
    for (int i = 0; i < 4; ++i) {
      int c = tid + 256 * i;
      int row = c >> 4, cc = c & 15;
      int sw = (row * 16 + ((cc & 8) | ((cc & 7) ^ (row & 7)))) * 8;
      *(float4*)&Vts[sw] =
          *(const float4*)&vtb[(size_t)(kh * 64 + row) * 2048 + t0 + cc * 8];
    }
    __syncthreads();
    const int qr = wid * 16 + l15;
    bf16x8 aq[2];
#pragma unroll
    for (int ks = 0; ks < 2; ++ks) {
      int c16 = ks * 4 + lq;
      aq[ks] = *(const bf16x8*)&Qs[(qr * 8 + (c16 ^ (qr & 7))) * 8];
    }
    f32x4 sv[2][4];
    const int nst = half + 1;
    for (int st = 0; st < nst; ++st)
#pragma unroll
      for (int nt = 0; nt < 4; ++nt) {
        int kr = st * 64 + nt * 16 + l15;
        bf16x8 bk0 = *(const bf16x8*)&Ks[(kr * 8 + ((0 + lq) ^ (kr & 7))) * 8];
        bf16x8 bk1 = *(const bf16x8*)&Ks[(kr * 8 + ((4 + lq) ^ (kr & 7))) * 8];
        f32x4 z = {0.f, 0.f, 0.f, 0.f};
        z = MFMA16(aq[0], bk0, z);
        z = MFMA16(aq[1], bk1, z);
        sv[st][nt] = z;
      }
    float mrow[4], ssum[4];
#pragma unroll
    for (int r = 0; r < 4; ++r) mrow[r] = -1e30f;
    for (int st = 0; st < nst; ++st)
#pragma unroll
      for (int nt = 0; nt < 4; ++nt) {
        int col = st * 64 + nt * 16 + l15;
#pragma unroll
        for (int r = 0; r < 4; ++r) {
          int row = half * 64 + wid * 16 + lq * 4 + r;
          float v = (col <= row) ? sv[st][nt][r] * 0.125f : -1e30f;
          sv[st][nt][r] = v;
          mrow[r] = fmaxf(mrow[r], v);
        }
      }
#pragma unroll
    for (int r = 0; r < 4; ++r) {
      for (int off = 1; off < 16; off <<= 1)
        mrow[r] = fmaxf(mrow[r], __shfl_xor(mrow[r], off, 64));
      ssum[r] = 0.f;
    }
    for (int st = 0; st < nst; ++st)
#pragma unroll
      for (int nt = 0; nt < 4; ++nt) {
        int col = st * 64 + nt * 16 + l15;
#pragma unroll
        for (int r = 0; r < 4; ++r) {
          float e = __expf(sv[st][nt][r] - mrow[r]);
          ssum[r] += e;
          int row = wid * 16 + lq * 4 + r;
          int c16 = col >> 3;
          Ps[(row * 16 + ((c16 & 8) | ((c16 & 7) ^ (row & 7)))) * 8 + (col & 7)] =
              f2b(e);
        }
      }
#pragma unroll
    for (int r = 0; r < 4; ++r) {
      for (int off = 1; off < 16; off <<= 1) ssum[r] += __shfl_xor(ssum[r], off, 64);
      ssum[r] = 1.f / ssum[r];
    }
    __syncthreads();
    f32x4 o[4];
#pragma unroll
    for (int nt = 0; nt < 4; ++nt) o[nt] = {0.f, 0.f, 0.f, 0.f};
    for (int ks = 0; ks < nst * 2; ++ks) {
      int c16 = ks * 4 + lq;
      bf16x8 ap = *(const bf16x8*)&Ps[(qr * 16 + ((c16 & 8) | ((c16 & 7) ^ (qr & 7)))) * 8];
#pragma unroll
      for (int nt = 0; nt < 4; ++nt) {
        int vr = nt * 16 + l15;
        bf16x8 bv = *(const bf16x8*)&Vts[(vr * 16 + ((c16 & 8) | ((c16 & 7) ^ (vr & 7)))) * 8];
        o[nt] = MFMA16(ap, bv, o[nt]);
      }
    }
#pragma unroll
    for (int nt = 0; nt < 4; ++nt)
#pragma unroll
      for (int r = 0; r < 4; ++r) {
        int row_g = t0 + half * 64 + wid * 16 + lq * 4 + r;
        int colg = h * 64 + nt * 16 + l15;
        yl[(size_t)row_g * 1024 + colg] = f2b(o[nt][r] * ssum[r]);
      }
  }
}

// ---------------------------------------------------------------------------
// RMSNorm over y = y0 + y1 + ylocal (bf16 partials); writes yn bf16.
// ---------------------------------------------------------------------------
__global__ __launch_bounds__(256) void rmsnorm_fuse(
    const short* __restrict__ y0, const short* __restrict__ y1,
    const short* __restrict__ ylc, const float* __restrict__ w,
    short* __restrict__ yn) {
  const int t = blockIdx.x, tid = threadIdx.x;
  __shared__ float red[4];
  __shared__ float rowv[1024];
  __shared__ float scale_sh;
  float ssum = 0.f;
  for (int c = tid; c < 1024; c += 256) {
    size_t idx = (size_t)t * 1024 + c;
    float v = b2f(y0[idx]) + b2f(y1[idx]) + b2f(ylc[idx]);
    rowv[c] = v;
    ssum = fmaf(v, v, ssum);
  }
  for (int off = 32; off > 0; off >>= 1) ssum += __shfl_down(ssum, off, 64);
  const int lane = tid & 63, wd = tid >> 6;
  if (lane == 0) red[wd] = ssum;
  __syncthreads();
  if (tid == 0)
    scale_sh = rsqrtf((red[0] + red[1] + red[2] + red[3]) * (1.0f / 1024.0f) + 1e-5f);
  __syncthreads();
  const float scale = scale_sh;
  for (int c = tid; c < 1024; c += 256)
    yn[(size_t)t * 1024 + c] = f2b(rowv[c] * scale * w[c]);
}

// ---------------------------------------------------------------------------
extern "C" void kernel_launch(void* const* d_in, const int* in_sizes, int n_in,
                              void* d_out, int out_size, void* d_ws,
                              size_t ws_size, hipStream_t stream) {
  const float* x = (const float*)d_in[0];
  const float* Wq = (const float*)d_in[1];
  const float* Wk = (const float*)d_in[2];
  const float* Wv = (const float*)d_in[3];
  const float* Wc = (const float*)d_in[4];
  const float* Wg = (const float*)d_in[5];
  const float* bg = (const float*)d_in[6];
  const float* rmsw = (const float*)d_in[7];
  float* out = (float*)d_out;

  short* wqkvT = (short*)d_ws;               // [1536][1024]
  short* wcT = wqkvT + 1536 * 1024;          // [1024][1024]
  short* qkvb = wcT + 1024 * 1024;           // [2048][1536] (v region unused)
  short* vtb = qkvb + 2048 * 1536;           // [256][2048]
  float* gw = (float*)(vtb + 256 * 2048);    // [2048][16]
  float* lacw = gw + 2048 * 16;              // [16][2048]
  float* inscw = lacw + 16 * 2048;           // [16][2048]
  short* xb = (short*)(inscw + 16 * 2048);   // [2048][1024]
  short* y0 = xb;                            // alias: xb dead after qkv GEMM
  short* y1 = xb + 2048 * 1024;
  short* ylc = y1 + 2048 * 1024;
  short* yn = ylc + 2048 * 1024;

  prep_fused<<<5632, 256, 0, stream>>>(x, Wq, Wk, Wv, Wc, Wg, bg, xb, wqkvT,
                                       wcT, gw);
  qkv_gemm_fused<<<784, 256, 0, stream>>>(xb, wqkvT, qkvb, vtb, gw, lacw,
                                          inscw);
  attn_fused<<<dim3(32, 16, 2), 256, 0, stream>>>(qkvb, vtb, lacw, inscw, y0,
                                                  y1, ylc);
  rmsnorm_fuse<<<2048, 256, 0, stream>>>(y0, y1, ylc, rmsw, yn);
  out_gemm<<<512, 256, 0, stream>>>(yn, wcT, out, 2048, 1024, 1024, 16);
}

// Round 8
// 147.092 us; speedup vs baseline: 4.3252x; 1.0216x over previous
//
#include <hip/hip_runtime.h>
#include <hip/hip_bf16.h>

// Dtype contract (established rounds 0-3): ALL inputs fp32, OUTPUT fp32
// (harness compares in bf16 domain, threshold ~2% of max => bf16 MFMA safe).
// Dims: B=1, T=2048, C=1024, H=16, HKV=4, DH=64, WIN=128.
// Round 8: global decayed attention rewritten as CHUNKED LINEAR SCAN:
//   intra-chunk diag tile + state S_c (DH x DH per head) recurrence
//   S_c = a_c S_{c-1} + B_{c-1},  B_c = sum_{s in c} e^{La_E-La_s} w_s k_s v_s^T
// Work drops 8.6 -> ~1.1 GFLOP; all exponents <= 0 (La non-increasing).
// qkv epilogue additionally writes rope'd k^T (ktb) for the state matmul.

typedef __attribute__((ext_vector_type(8))) short bf16x8;  // 8 bf16 = 4 VGPR
typedef __attribute__((ext_vector_type(4))) float f32x4;

#define MFMA16(a, b, c) __builtin_amdgcn_mfma_f32_16x16x32_bf16(a, b, c, 0, 0, 0)
#define LN10000_OVER_32 0.28782313662425575f

__device__ __forceinline__ short f2b(float f) {
  __hip_bfloat16 h = __float2bfloat16(f);
  return *reinterpret_cast<short*>(&h);
}
__device__ __forceinline__ float b2f(short s) {
  return __uint_as_float(((unsigned)(unsigned short)s) << 16);
}
// Async 16B/lane global->LDS copy. LDS dest = wave-uniform base + lane*16.
__device__ __forceinline__ void gload16(const void* g, void* l) {
  __builtin_amdgcn_global_load_lds(
      (const __attribute__((address_space(1))) void*)g,
      (__attribute__((address_space(3))) void*)l, 16, 0, 0);
}

// ---------------------------------------------------------------------------
// prep_fused (unchanged from round 7)
// ---------------------------------------------------------------------------
__device__ __forceinline__ void transpose_cvt_body(
    const float* __restrict__ src, short* __restrict__ dst, int R, int C,
    int bx, int by, float* ts /* [32*33] */) {
  int c0 = bx * 32, r0 = by * 32;
  int tr = threadIdx.x >> 3, tc = (threadIdx.x & 7) * 4;
  float4 v = *(const float4*)&src[(size_t)(r0 + tr) * C + c0 + tc];
  ts[tr * 33 + tc] = v.x;
  ts[tr * 33 + tc + 1] = v.y;
  ts[tr * 33 + tc + 2] = v.z;
  ts[tr * 33 + tc + 3] = v.w;
  __syncthreads();
  alignas(8) short o[4];
#pragma unroll
  for (int i = 0; i < 4; ++i) o[i] = f2b(ts[(tc + i) * 33 + tr]);
  *(uint2*)&dst[(size_t)(c0 + tr) * R + r0 + tc] = *(uint2*)o;
}

__global__ __launch_bounds__(256) void prep_fused(
    const float* __restrict__ x, const float* __restrict__ Wq,
    const float* __restrict__ Wk, const float* __restrict__ Wv,
    const float* __restrict__ Wc, const float* __restrict__ Wg,
    const float* __restrict__ bg, short* __restrict__ xb,
    short* __restrict__ wqkvT, short* __restrict__ wcT,
    float* __restrict__ g) {
  __shared__ float ts[32 * 33];
  const int j = blockIdx.x;
  const int tid = threadIdx.x;
  if (j < 2048) {
    const int t = j;
    const int h = tid & 15, chunk = tid >> 4;
    const float* xr = x + (size_t)t * 1024 + chunk * 64;
    const float* wg = Wg + (size_t)chunk * 64 * 16 + h;
    float acc = 0.f;
#pragma unroll
    for (int c = 0; c < 64; c += 4) {
      float4 xv = *(const float4*)(xr + c);
      acc = fmaf(xv.x, wg[(c + 0) * 16], acc);
      acc = fmaf(xv.y, wg[(c + 1) * 16], acc);
      acc = fmaf(xv.z, wg[(c + 2) * 16], acc);
      acc = fmaf(xv.w, wg[(c + 3) * 16], acc);
    }
    ts[chunk * 16 + h] = acc;
    __syncthreads();
    if (tid < 16) {
      float s = bg[tid];
#pragma unroll
      for (int i = 0; i < 16; ++i) s += ts[i * 16 + tid];
      g[t * 16 + tid] = s;
    }
  } else if (j < 3072) {
    int i = ((j - 2048) * 256 + tid) * 8;
    float4 a = *(const float4*)(x + i);
    float4 b = *(const float4*)(x + i + 4);
    alignas(16) short o[8] = {f2b(a.x), f2b(a.y), f2b(a.z), f2b(a.w),
                              f2b(b.x), f2b(b.y), f2b(b.z), f2b(b.w)};
    *(float4*)(xb + i) = *(float4*)o;
  } else if (j < 4096) {
    int jj = j - 3072;
    transpose_cvt_body(Wq, wqkvT, 1024, 1024, jj & 31, jj >> 5, ts);
  } else if (j < 4352) {
    int jj = j - 4096;
    transpose_cvt_body(Wk, wqkvT + 1024 * 1024, 1024, 256, jj & 7, jj >> 3, ts);
  } else if (j < 4608) {
    int jj = j - 4352;
    transpose_cvt_body(Wv, wqkvT + 1280 * 1024, 1024, 256, jj & 7, jj >> 3, ts);
  } else {
    int jj = j - 4608;
    transpose_cvt_body(Wc, wcT, 1024, 1024, jj & 31, jj >> 5, ts);
  }
}

// ---------------------------------------------------------------------------
// QKV GEMM + gate scan. k-tiles (bx 16..19) now ALSO write rope'd k^T -> ktb.
// ---------------------------------------------------------------------------
__global__ __launch_bounds__(256) void qkv_gemm_fused(
    const short* __restrict__ A, const short* __restrict__ Bt,
    short* __restrict__ qkvb, short* __restrict__ vtb,
    short* __restrict__ ktb, const float* __restrict__ g,
    float* __restrict__ lac, float* __restrict__ insc) {
  __shared__ short As[64 * 64];
  __shared__ short Bs[64 * 64];
  __shared__ float part[256];
  const int id = blockIdx.x;
  const int tid = threadIdx.x;
  if (id >= 768) {
    const int h = id - 768;
    float vals[8];
    float local = 0.f;
#pragma unroll
    for (int i = 0; i < 8; ++i) {
      int t = tid * 8 + i;
      float gv = g[t * 16 + h];
      float la = (gv > 0.f) ? -log1pf(expf(-gv)) : (gv - log1pf(expf(gv)));
      insc[h * 2048 + t] = 1.f / (1.f + expf(gv));
      vals[i] = la;
      local += la;
    }
    part[tid] = local;
    __syncthreads();
    for (int off = 1; off < 256; off <<= 1) {
      float add = (tid >= off) ? part[tid - off] : 0.f;
      __syncthreads();
      part[tid] += add;
      __syncthreads();
    }
    float run = (tid > 0) ? part[tid - 1] : 0.f;
#pragma unroll
    for (int i = 0; i < 8; ++i) {
      run += vals[i];
      lac[h * 2048 + tid * 8 + i] = run;
    }
    return;
  }
  const int lane = tid & 63, wid = tid >> 6;
  const int l15 = lane & 15, lq = lane >> 4;
  const int jlin = id >> 3;
  const int by = (id & 7) + 8 * (jlin / 24);
  const int bx = jlin % 24;
  const int m0 = by * 64, n0 = bx * 64;
  const int K = 1024;
  const int srow = lane >> 3;
  const int sc16 = (lane & 7) ^ srow;
  f32x4 acc[4];
#pragma unroll
  for (int nt = 0; nt < 4; ++nt) acc[nt] = {0.f, 0.f, 0.f, 0.f};
  for (int kt = 0; kt < K; kt += 64) {
    __syncthreads();
#pragma unroll
    for (int i = 0; i < 2; ++i) {
      int jj = wid * 2 + i;
      int row = jj * 8 + srow;
      gload16(A + (size_t)(m0 + row) * K + kt + sc16 * 8, &As[jj * 512]);
      gload16(Bt + (size_t)(n0 + row) * K + kt + sc16 * 8, &Bs[jj * 512]);
    }
    __syncthreads();
    bf16x8 af[2], bfr[4][2];
#pragma unroll
    for (int ks = 0; ks < 2; ++ks) {
      int c16 = ks * 4 + lq;
      int ar = wid * 16 + l15;
      af[ks] = *(const bf16x8*)&As[(ar * 8 + (c16 ^ (ar & 7))) * 8];
#pragma unroll
      for (int nt = 0; nt < 4; ++nt) {
        int br = nt * 16 + l15;
        bfr[nt][ks] = *(const bf16x8*)&Bs[(br * 8 + (c16 ^ (br & 7))) * 8];
      }
    }
#pragma unroll
    for (int ks = 0; ks < 2; ++ks)
#pragma unroll
      for (int nt = 0; nt < 4; ++nt)
        acc[nt] = MFMA16(af[ks], bfr[nt][ks], acc[nt]);
  }
  const int row0 = m0 + wid * 16 + lq * 4;
  if (bx >= 20) {
    // V tile: transposed write vtb[d][t]
#pragma unroll
    for (int nt = 0; nt < 4; ++nt) {
      int vcol = (n0 - 1280) + nt * 16 + l15;
      alignas(8) short o4[4];
#pragma unroll
      for (int r = 0; r < 4; ++r) o4[r] = f2b(acc[nt][r]);
      *(uint2*)&vtb[(size_t)vcol * 2048 + row0] = *(uint2*)o4;
    }
    return;
  }
  const bool isk = (bx >= 16);
#pragma unroll
  for (int nt = 0; nt < 2; ++nt) {
    int d = nt * 16 + l15;  // 0..31
    float ivf = __expf(-LN10000_OVER_32 * (float)d);
    alignas(8) short oa[4], ob[4];
#pragma unroll
    for (int r = 0; r < 4; ++r) {
      int row_g = row0 + r;
      float th = (float)row_g * ivf;
      float cs = cosf(th), sn = sinf(th);
      float a = acc[nt][r], b = acc[nt + 2][r];
      oa[r] = f2b(a * cs - b * sn);
      ob[r] = f2b(b * cs + a * sn);
      qkvb[(size_t)row_g * 1536 + n0 + d] = oa[r];
      qkvb[(size_t)row_g * 1536 + n0 + d + 32] = ob[r];
    }
    if (isk) {
      int dk = n0 - 1024 + d;  // 0..255 within ktb
      *(uint2*)&ktb[(size_t)dk * 2048 + row0] = *(uint2*)oa;
      *(uint2*)&ktb[(size_t)(dk + 32) * 2048 + row0] = *(uint2*)ob;
    }
  }
}

// ---------------------------------------------------------------------------
// p1_local: z=0 chunk-state B_c (stored transposed: Bmat[h][c][e][d] =
//   sum_s v_s[e] * g_s * k_s[d],  g_s = e^{La_E - La_s} * insc_s),
// z=1 local windowed softmax attention (verified round-6 body).
// ---------------------------------------------------------------------------
__global__ __launch_bounds__(256) void p1_local(
    const short* __restrict__ qkv, const short* __restrict__ vtb,
    const short* __restrict__ ktb, const float* __restrict__ lac,
    const float* __restrict__ insc, float* __restrict__ Bmat,
    short* __restrict__ yl) {
  __shared__ short SA[64 * 64];
  __shared__ short SB[128 * 64];
  __shared__ short SC[64 * 128];
  __shared__ short SD[64 * 128];
  __shared__ float lacs[64], inss[64], gvals[64];
  const int tid = threadIdx.x, lane = tid & 63, wid = tid >> 6;
  const int l15 = lane & 15, lq = lane >> 4;
  const int h = blockIdx.y;
  const int kh = h >> 2;
  if (blockIdx.z == 0) {
    // ---- chunk state ----
    const int c = blockIdx.x;
    short* Ks = SB;
    short* Vts = SC;
    const int srow = lane >> 3;
    const int sc16 = (lane & 7) ^ srow;
#pragma unroll
    for (int i = 0; i < 2; ++i) {
      int jj = wid * 2 + i;
      int row = jj * 8 + srow;
      gload16(ktb + (size_t)(kh * 64 + row) * 2048 + c * 64 + sc16 * 8,
              &Ks[jj * 512]);
      gload16(vtb + (size_t)(kh * 64 + row) * 2048 + c * 64 + sc16 * 8,
              &Vts[jj * 512]);
    }
    if (tid < 64) {
      lacs[tid] = lac[h * 2048 + c * 64 + tid];
      inss[tid] = insc[h * 2048 + c * 64 + tid];
    }
    __syncthreads();
    if (tid < 64)
      gvals[tid] = __expf(fminf(lacs[63] - lacs[tid], 0.f)) * inss[tid];
    __syncthreads();
    const int er = wid * 16 + l15;
    bf16x8 av[2];
#pragma unroll
    for (int ks = 0; ks < 2; ++ks) {
      int c16 = ks * 4 + lq;
      bf16x8 raw = *(const bf16x8*)&Vts[(er * 8 + (c16 ^ (er & 7))) * 8];
      float4 g0 = *(const float4*)&gvals[c16 * 8];
      float4 g1 = *(const float4*)&gvals[c16 * 8 + 4];
      float gv[8] = {g0.x, g0.y, g0.z, g0.w, g1.x, g1.y, g1.z, g1.w};
      bf16x8 sc;
#pragma unroll
      for (int jx = 0; jx < 8; ++jx) sc[jx] = f2b(b2f(raw[jx]) * gv[jx]);
      av[ks] = sc;
    }
    f32x4 acc[4];
#pragma unroll
    for (int nt = 0; nt < 4; ++nt) acc[nt] = {0.f, 0.f, 0.f, 0.f};
#pragma unroll
    for (int ks = 0; ks < 2; ++ks) {
      int c16 = ks * 4 + lq;
#pragma unroll
      for (int nt = 0; nt < 4; ++nt) {
        int dr = nt * 16 + l15;
        bf16x8 bk = *(const bf16x8*)&Ks[(dr * 8 + (c16 ^ (dr & 7))) * 8];
        acc[nt] = MFMA16(av[ks], bk, acc[nt]);
      }
    }
    float* Bout = Bmat + (size_t)(h * 32 + c) * 4096;
#pragma unroll
    for (int nt = 0; nt < 4; ++nt)
#pragma unroll
      for (int r = 0; r < 4; ++r) {
        int e = wid * 16 + lq * 4 + r;
        Bout[e * 64 + nt * 16 + l15] = acc[nt][r];
      }
  } else {
    // ---- local windowed softmax attention ----
    const int half = blockIdx.x & 1, wb = blockIdx.x >> 1;
    const int t0 = wb * 128;
    short* Qs = SA;
    short* Ks = SB;
    short* Vts = SC;
    short* Ps = SD;
#pragma unroll
    for (int i = 0; i < 2; ++i) {
      int cix = tid + 256 * i;
      int row = cix >> 3, cc = cix & 7;
      *(float4*)&Qs[(row * 8 + (cc ^ (row & 7))) * 8] =
          *(const float4*)&qkv[(size_t)(t0 + half * 64 + row) * 1536 + h * 64 + cc * 8];
    }
#pragma unroll
    for (int i = 0; i < 4; ++i) {
      int cix = tid + 256 * i;
      int row = cix >> 3, cc = cix & 7;
      *(float4*)&Ks[(row * 8 + (cc ^ (row & 7))) * 8] =
          *(const float4*)&qkv[(size_t)(t0 + row) * 1536 + 1024 + kh * 64 + cc * 8];
    }
#pragma unroll
    for (int i = 0; i < 4; ++i) {
      int cix = tid + 256 * i;
      int row = cix >> 4, cc = cix & 15;
      int sw = (row * 16 + ((cc & 8) | ((cc & 7) ^ (row & 7)))) * 8;
      *(float4*)&Vts[sw] =
          *(const float4*)&vtb[(size_t)(kh * 64 + row) * 2048 + t0 + cc * 8];
    }
    __syncthreads();
    const int qr = wid * 16 + l15;
    bf16x8 aq[2];
#pragma unroll
    for (int ks = 0; ks < 2; ++ks) {
      int c16 = ks * 4 + lq;
      aq[ks] = *(const bf16x8*)&Qs[(qr * 8 + (c16 ^ (qr & 7))) * 8];
    }
    f32x4 sv[2][4];
    const int nst = half + 1;
    for (int st = 0; st < nst; ++st)
#pragma unroll
      for (int nt = 0; nt < 4; ++nt) {
        int kr = st * 64 + nt * 16 + l15;
        bf16x8 bk0 = *(const bf16x8*)&Ks[(kr * 8 + ((0 + lq) ^ (kr & 7))) * 8];
        bf16x8 bk1 = *(const bf16x8*)&Ks[(kr * 8 + ((4 + lq) ^ (kr & 7))) * 8];
        f32x4 z = {0.f, 0.f, 0.f, 0.f};
        z = MFMA16(aq[0], bk0, z);
        z = MFMA16(aq[1], bk1, z);
        sv[st][nt] = z;
      }
    float mrow[4], ssum[4];
#pragma unroll
    for (int r = 0; r < 4; ++r) mrow[r] = -1e30f;
    for (int st = 0; st < nst; ++st)
#pragma unroll
      for (int nt = 0; nt < 4; ++nt) {
        int col = st * 64 + nt * 16 + l15;
#pragma unroll
        for (int r = 0; r < 4; ++r) {
          int row = half * 64 + wid * 16 + lq * 4 + r;
          float v = (col <= row) ? sv[st][nt][r] * 0.125f : -1e30f;
          sv[st][nt][r] = v;
          mrow[r] = fmaxf(mrow[r], v);
        }
      }
#pragma unroll
    for (int r = 0; r < 4; ++r) {
      for (int off = 1; off < 16; off <<= 1)
        mrow[r] = fmaxf(mrow[r], __shfl_xor(mrow[r], off, 64));
      ssum[r] = 0.f;
    }
    for (int st = 0; st < nst; ++st)
#pragma unroll
      for (int nt = 0; nt < 4; ++nt) {
        int col = st * 64 + nt * 16 + l15;
#pragma unroll
        for (int r = 0; r < 4; ++r) {
          float e = __expf(sv[st][nt][r] - mrow[r]);
          ssum[r] += e;
          int row = wid * 16 + lq * 4 + r;
          int c16 = col >> 3;
          Ps[(row * 16 + ((c16 & 8) | ((c16 & 7) ^ (row & 7)))) * 8 + (col & 7)] =
              f2b(e);
        }
      }
#pragma unroll
    for (int r = 0; r < 4; ++r) {
      for (int off = 1; off < 16; off <<= 1) ssum[r] += __shfl_xor(ssum[r], off, 64);
      ssum[r] = 1.f / ssum[r];
    }
    __syncthreads();
    f32x4 o[4];
#pragma unroll
    for (int nt = 0; nt < 4; ++nt) o[nt] = {0.f, 0.f, 0.f, 0.f};
    for (int ks = 0; ks < nst * 2; ++ks) {
      int c16 = ks * 4 + lq;
      bf16x8 ap = *(const bf16x8*)&Ps[(qr * 16 + ((c16 & 8) | ((c16 & 7) ^ (qr & 7)))) * 8];
#pragma unroll
      for (int nt = 0; nt < 4; ++nt) {
        int vr = nt * 16 + l15;
        bf16x8 bv = *(const bf16x8*)&Vts[(vr * 16 + ((c16 & 8) | ((c16 & 7) ^ (vr & 7)))) * 8];
        o[nt] = MFMA16(ap, bv, o[nt]);
      }
    }
#pragma unroll
    for (int nt = 0; nt < 4; ++nt)
#pragma unroll
      for (int r = 0; r < 4; ++r) {
        int row_g = t0 + half * 64 + wid * 16 + lq * 4 + r;
        int colg = h * 64 + nt * 16 + l15;
        yl[(size_t)row_g * 1024 + colg] = f2b(o[nt][r] * ssum[r]);
      }
  }
}

// ---------------------------------------------------------------------------
// State scan: St[h][c] = a_c * St[h][c-1] + B[h][c-1], St[h][0] = 0,
// a_c = e^{lacE[c-1]-lacE[c-2]}. St stored bf16 [e][d]. Grid 16 (h), 256 thr.
// ---------------------------------------------------------------------------
__global__ __launch_bounds__(256) void scan_kernel(
    const float* __restrict__ Bmat, const float* __restrict__ lac,
    short* __restrict__ St) {
  const int h = blockIdx.x, tid = threadIdx.x;
  __shared__ float lacE[32];
  if (tid < 32) lacE[tid] = lac[h * 2048 + tid * 64 + 63];
  __syncthreads();
  const int base = tid * 16;
  float S[16];
#pragma unroll
  for (int i = 0; i < 16; ++i) S[i] = 0.f;
  alignas(16) short z16[16];
#pragma unroll
  for (int i = 0; i < 16; ++i) z16[i] = 0;
  *(uint4*)&St[(size_t)(h * 32) * 4096 + base] = *(uint4*)z16;
  *(uint4*)&St[(size_t)(h * 32) * 4096 + base + 8] = *(uint4*)(z16 + 8);
  for (int c = 1; c < 32; ++c) {
    float a = (c >= 2) ? __expf(fminf(lacE[c - 1] - lacE[c - 2], 0.f)) : 0.f;
    const float* Bp = Bmat + (size_t)(h * 32 + c - 1) * 4096 + base;
    float4 b0 = *(const float4*)(Bp + 0);
    float4 b1 = *(const float4*)(Bp + 4);
    float4 b2 = *(const float4*)(Bp + 8);
    float4 b3 = *(const float4*)(Bp + 12);
    float bb[16] = {b0.x, b0.y, b0.z, b0.w, b1.x, b1.y, b1.z, b1.w,
                    b2.x, b2.y, b2.z, b2.w, b3.x, b3.y, b3.z, b3.w};
    alignas(16) short o16[16];
#pragma unroll
    for (int i = 0; i < 16; ++i) {
      S[i] = fmaf(a, S[i], bb[i]);
      o16[i] = f2b(S[i]);
    }
    *(uint4*)&St[(size_t)(h * 32 + c) * 4096 + base] = *(uint4*)o16;
    *(uint4*)&St[(size_t)(h * 32 + c) * 4096 + base + 8] = *(uint4*)(o16 + 8);
  }
}

// ---------------------------------------------------------------------------
// Phase 3: per (chunk c, head h): intra-chunk diag attention + q'@S_c.
// y[t][e] = intra + e^{La_t - La_prevEnd} * (Q @ St_c^T)[t][e].  Grid (32,16).
// ---------------------------------------------------------------------------
__global__ __launch_bounds__(256) void global_attn_v3(
    const short* __restrict__ qkv, const short* __restrict__ vtb,
    const short* __restrict__ St, const float* __restrict__ lac,
    const float* __restrict__ insc, short* __restrict__ yg) {
  const int c = blockIdx.x, h = blockIdx.y;
  const int kh = h >> 2;
  __shared__ short Qs[64 * 64], Ks[64 * 64], Vts[64 * 64], Sts[64 * 64],
      Ps[64 * 64];
  __shared__ float lacq[64], inss[64];
  __shared__ float laprev_sh;
  const int tid = threadIdx.x, lane = tid & 63, wid = tid >> 6;
  const int l15 = lane & 15, lq = lane >> 4;
  const int srow = lane >> 3;
  const int sc16 = (lane & 7) ^ srow;
#pragma unroll
  for (int i = 0; i < 2; ++i) {
    int jj = wid * 2 + i;
    int row = jj * 8 + srow;
    gload16(qkv + (size_t)(c * 64 + row) * 1536 + h * 64 + sc16 * 8,
            &Qs[jj * 512]);
    gload16(qkv + (size_t)(c * 64 + row) * 1536 + 1024 + kh * 64 + sc16 * 8,
            &Ks[jj * 512]);
    gload16(vtb + (size_t)(kh * 64 + row) * 2048 + c * 64 + sc16 * 8,
            &Vts[jj * 512]);
    gload16(St + (size_t)(h * 32 + c) * 4096 + row * 64 + sc16 * 8,
            &Sts[jj * 512]);
  }
  if (tid < 64) {
    lacq[tid] = lac[h * 2048 + c * 64 + tid];
    inss[tid] = insc[h * 2048 + c * 64 + tid];
  }
  if (tid == 0) laprev_sh = (c > 0) ? lac[h * 2048 + c * 64 - 1] : 1e30f;
  __syncthreads();
  const int qr = wid * 16 + l15;
  bf16x8 aq[2];
#pragma unroll
  for (int ks = 0; ks < 2; ++ks) {
    int c16 = ks * 4 + lq;
    aq[ks] = *(const bf16x8*)&Qs[(qr * 8 + (c16 ^ (qr & 7))) * 8];
  }
  // S = Q @ K^T (diag tile)
  f32x4 sv[4];
#pragma unroll
  for (int nt = 0; nt < 4; ++nt) {
    int kr = nt * 16 + l15;
    bf16x8 bk0 = *(const bf16x8*)&Ks[(kr * 8 + ((0 + lq) ^ (kr & 7))) * 8];
    bf16x8 bk1 = *(const bf16x8*)&Ks[(kr * 8 + ((4 + lq) ^ (kr & 7))) * 8];
    f32x4 z = {0.f, 0.f, 0.f, 0.f};
    z = MFMA16(aq[0], bk0, z);
    z = MFMA16(aq[1], bk1, z);
    sv[nt] = z;
  }
  // decay + causal mask -> P
#pragma unroll
  for (int nt = 0; nt < 4; ++nt) {
    int col = nt * 16 + l15;
    float ls = lacq[col], is = inss[col];
#pragma unroll
    for (int r = 0; r < 4; ++r) {
      int row = wid * 16 + lq * 4 + r;
      float d = lacq[row] - ls;
      float w = __expf(fminf(d, 0.f)) * is;
      if (col > row) w = 0.f;
      Ps[(row * 8 + ((col >> 3) ^ (row & 7))) * 8 + (col & 7)] = f2b(sv[nt][r] * w);
    }
  }
  // inter: Oi = Q @ St^T  (independent of Ps; overlaps the barrier)
  f32x4 oi[4];
#pragma unroll
  for (int nt = 0; nt < 4; ++nt) {
    int er = nt * 16 + l15;
    bf16x8 bs0 = *(const bf16x8*)&Sts[(er * 8 + ((0 + lq) ^ (er & 7))) * 8];
    bf16x8 bs1 = *(const bf16x8*)&Sts[(er * 8 + ((4 + lq) ^ (er & 7))) * 8];
    f32x4 z = {0.f, 0.f, 0.f, 0.f};
    z = MFMA16(aq[0], bs0, z);
    z = MFMA16(aq[1], bs1, z);
    oi[nt] = z;
  }
  __syncthreads();
  // O = P @ V
  bf16x8 ap[2];
#pragma unroll
  for (int ks = 0; ks < 2; ++ks) {
    int c16 = ks * 4 + lq;
    ap[ks] = *(const bf16x8*)&Ps[(qr * 8 + (c16 ^ (qr & 7))) * 8];
  }
  f32x4 o[4];
#pragma unroll
  for (int nt = 0; nt < 4; ++nt) {
    int vr = nt * 16 + l15;
    bf16x8 bv0 = *(const bf16x8*)&Vts[(vr * 8 + ((0 + lq) ^ (vr & 7))) * 8];
    bf16x8 bv1 = *(const bf16x8*)&Vts[(vr * 8 + ((4 + lq) ^ (vr & 7))) * 8];
    f32x4 z = {0.f, 0.f, 0.f, 0.f};
    z = MFMA16(ap[0], bv0, z);
    z = MFMA16(ap[1], bv1, z);
    o[nt] = z;
  }
  const float laprev = laprev_sh;
#pragma unroll
  for (int r = 0; r < 4; ++r) {
    int row = wid * 16 + lq * 4 + r;
    float rfac = __expf(fminf(lacq[row] - laprev, 0.f));
    int row_g = c * 64 + row;
#pragma unroll
    for (int nt = 0; nt < 4; ++nt) {
      int colg = h * 64 + nt * 16 + l15;
      yg[(size_t)row_g * 1024 + colg] = f2b(o[nt][r] + rfac * oi[nt][r]);
    }
  }
}

// ---------------------------------------------------------------------------
// RMSNorm over y = yg + ylocal; writes yn bf16.
// ---------------------------------------------------------------------------
__global__ __launch_bounds__(256) void rmsnorm_fuse(
    const short* __restrict__ yg, const short* __restrict__ ylc,
    const float* __restrict__ w, short* __restrict__ yn) {
  const int t = blockIdx.x, tid = threadIdx.x;
  __shared__ float red[4];
  __shared__ float rowv[1024];
  __shared__ float scale_sh;
  float ssum = 0.f;
  for (int c = tid; c < 1024; c += 256) {
    size_t idx = (size_t)t * 1024 + c;
    float v = b2f(yg[idx]) + b2f(ylc[idx]);
    rowv[c] = v;
    ssum = fmaf(v, v, ssum);
  }
  for (int off = 32; off > 0; off >>= 1) ssum += __shfl_down(ssum, off, 64);
  const int lane = tid & 63, wd = tid >> 6;
  if (lane == 0) red[wd] = ssum;
  __syncthreads();
  if (tid == 0)
    scale_sh = rsqrtf((red[0] + red[1] + red[2] + red[3]) * (1.0f / 1024.0f) + 1e-5f);
  __syncthreads();
  const float scale = scale_sh;
  for (int c = tid; c < 1024; c += 256)
    yn[(size_t)t * 1024 + c] = f2b(rowv[c] * scale * w[c]);
}

// ---------------------------------------------------------------------------
// Out projection GEMM (unchanged).
// ---------------------------------------------------------------------------
__global__ __launch_bounds__(256) void out_gemm(
    const short* __restrict__ A, const short* __restrict__ Bt,
    float* __restrict__ C, int M, int N, int K, int nbx) {
  __shared__ short As[64 * 64];
  __shared__ short Bs[64 * 64];
  const int tid = threadIdx.x, lane = tid & 63, wid = tid >> 6;
  const int l15 = lane & 15, lq = lane >> 4;
  const int id = blockIdx.x;
  const int jlin = id >> 3;
  const int by = (id & 7) + 8 * (jlin / nbx);
  const int bx = jlin % nbx;
  const int m0 = by * 64, n0 = bx * 64;
  const int srow = lane >> 3;
  const int sc16 = (lane & 7) ^ srow;
  f32x4 acc[4];
#pragma unroll
  for (int nt = 0; nt < 4; ++nt) acc[nt] = {0.f, 0.f, 0.f, 0.f};
  for (int kt = 0; kt < K; kt += 64) {
    __syncthreads();
#pragma unroll
    for (int i = 0; i < 2; ++i) {
      int jj = wid * 2 + i;
      int row = jj * 8 + srow;
      gload16(A + (size_t)(m0 + row) * K + kt + sc16 * 8, &As[jj * 512]);
      gload16(Bt + (size_t)(n0 + row) * K + kt + sc16 * 8, &Bs[jj * 512]);
    }
    __syncthreads();
    bf16x8 af[2], bfr[4][2];
#pragma unroll
    for (int ks = 0; ks < 2; ++ks) {
      int c16 = ks * 4 + lq;
      int ar = wid * 16 + l15;
      af[ks] = *(const bf16x8*)&As[(ar * 8 + (c16 ^ (ar & 7))) * 8];
#pragma unroll
      for (int nt = 0; nt < 4; ++nt) {
        int br = nt * 16 + l15;
        bfr[nt][ks] = *(const bf16x8*)&Bs[(br * 8 + (c16 ^ (br & 7))) * 8];
      }
    }
#pragma unroll
    for (int ks = 0; ks < 2; ++ks)
#pragma unroll
      for (int nt = 0; nt < 4; ++nt)
        acc[nt] = MFMA16(af[ks], bfr[nt][ks], acc[nt]);
  }
#pragma unroll
  for (int r = 0; r < 4; ++r) {
    int row_g = m0 + wid * 16 + lq * 4 + r;
#pragma unroll
    for (int nt = 0; nt < 4; ++nt)
      C[(size_t)row_g * N + n0 + nt * 16 + l15] = acc[nt][r];
  }
}

// ---------------------------------------------------------------------------
extern "C" void kernel_launch(void* const* d_in, const int* in_sizes, int n_in,
                              void* d_out, int out_size, void* d_ws,
                              size_t ws_size, hipStream_t stream) {
  const float* x = (const float*)d_in[0];
  const float* Wq = (const float*)d_in[1];
  const float* Wk = (const float*)d_in[2];
  const float* Wv = (const float*)d_in[3];
  const float* Wc = (const float*)d_in[4];
  const float* Wg = (const float*)d_in[5];
  const float* bg = (const float*)d_in[6];
  const float* rmsw = (const float*)d_in[7];
  float* out = (float*)d_out;

  short* wqkvT = (short*)d_ws;               // [1536][1024]
  short* wcT = wqkvT + 1536 * 1024;          // [1024][1024]
  short* qkvb = wcT + 1024 * 1024;           // [2048][1536] (v region unused)
  short* vtb = qkvb + 2048 * 1536;           // [256][2048]
  short* ktb = vtb + 256 * 2048;             // [256][2048]
  float* gw = (float*)(ktb + 256 * 2048);    // [2048][16]
  float* lacw = gw + 2048 * 16;              // [16][2048]
  float* inscw = lacw + 16 * 2048;           // [16][2048]
  float* Bmat = inscw + 16 * 2048;           // [16][32][64][64] f32
  short* Stb = (short*)(Bmat + 16 * 32 * 4096);  // [16][32][64][64] bf16
  short* xb = Stb + 16 * 32 * 4096;          // [2048][1024]
  short* yg = xb;                            // alias: xb dead after qkv GEMM
  short* ylc = xb + 2048 * 1024;
  short* yn = ylc + 2048 * 1024;

  prep_fused<<<5632, 256, 0, stream>>>(x, Wq, Wk, Wv, Wc, Wg, bg, xb, wqkvT,
                                       wcT, gw);
  qkv_gemm_fused<<<784, 256, 0, stream>>>(xb, wqkvT, qkvb, vtb, ktb, gw, lacw,
                                          inscw);
  p1_local<<<dim3(32, 16, 2), 256, 0, stream>>>(qkvb, vtb, ktb, lacw, inscw,
                                                Bmat, ylc);
  scan_kernel<<<16, 256, 0, stream>>>(Bmat, lacw, Stb);
  global_attn_v3<<<dim3(32, 16), 256, 0, stream>>>(qkvb, vtb, Stb, lacw, inscw,
                                                   yg);
  rmsnorm_fuse<<<2048, 256, 0, stream>>>(yg, ylc, rmsw, yn);
  out_gemm<<<512, 256, 0, stream>>>(yn, wcT, out, 2048, 1024, 1024, 16);
}